// Round 8
// baseline (926.946 us; speedup 1.0000x reference)
//
#include <hip/hip_runtime.h>
#include <hip/hip_cooperative_groups.h>
#include <hip/hip_bf16.h>
#include <math.h>

namespace cg = cooperative_groups;

#define N_NODES 4096
#define FDIM 512            // K of both GEMMs (F_in = H*D = 512)
#define D 64
#define H 8
#define NWORDS (N_NODES / 64)
#define S1 4                // layer-1 j-slabs
#define S2 32               // layer-2 j-slabs
#define NBLK 1024           // 4 blocks/CU x 256 CU, all co-resident
#define NTHR 128

typedef __attribute__((ext_vector_type(8))) short bf16x8;      // raw 16B of halfwords
typedef __attribute__((ext_vector_type(4))) float f32x4;
typedef __attribute__((ext_vector_type(8))) _Float16 f16x8;    // MFMA f16 operand
typedef __attribute__((ext_vector_type(2))) _Float16 f16x2;    // packed-pair math
typedef __attribute__((ext_vector_type(4))) unsigned int u32x4;

__device__ inline short f2h(float x) {                         // f32->f16 RNE
    _Float16 h = (_Float16)x;
    return __builtin_bit_cast(short, h);
}
__device__ inline float h2f(unsigned short u) {
    return (float)__builtin_bit_cast(_Float16, u);
}
__device__ inline f16x2 bcH(unsigned int u) { return __builtin_bit_cast(f16x2, u); }

__device__ inline int sext_bit(unsigned int v, int j) {        // all-ones iff bit j set
#if defined(__has_builtin) && __has_builtin(__builtin_amdgcn_sbfe)
    return __builtin_amdgcn_sbfe((int)v, j, 1);
#else
    return ((int)(v << (31 - j))) >> 31;
#endif
}

// monotonic float<->uint encoding so unsigned atomicMax == float max
__device__ inline unsigned fenc(float f) {
    unsigned u = __builtin_bit_cast(unsigned, f);
    return (u & 0x80000000u) ? ~u : (u | 0x80000000u);
}
__device__ inline float fdec(unsigned e) {
    unsigned u = (e & 0x80000000u) ? (e & 0x7FFFFFFFu) : ~e;
    return __builtin_bit_cast(float, u);
}

// async global->LDS 16B copy (DMA). LDS dst must be wave-uniform base + lane*16.
__device__ inline void gl2lds16(const void* g, void* l) {
#if defined(__has_builtin) && __has_builtin(__builtin_amdgcn_global_load_lds)
    __builtin_amdgcn_global_load_lds(
        (const __attribute__((address_space(1))) unsigned int*)g,
        (__attribute__((address_space(3))) unsigned int*)l, 16, 0, 0);
#else
    *(uint4*)l = *(const uint4*)g;
#endif
}

// per-block shared scratch, reused across phases (36,864 B -> 4 blocks/CU)
union Smem {
    struct { short Bt[2][8192]; short Esh[1024]; short Gsh[1024]; } a;  // accum phases
    struct { float csum[128]; float red[2]; } g;                        // gemm phases
};

// ================================================================ phase bodies
// ---- P0: preprocessing (grid-strided over 1024x128)
__device__ __forceinline__ void phase_pre(int b, int t,
    const int* __restrict__ adj, const float* __restrict__ x,
    const float* __restrict__ W, const float* __restrict__ Wo,
    unsigned* __restrict__ bits32, short* __restrict__ Xbf,
    short* __restrict__ WF, short* __restrict__ WoF,
    float* __restrict__ cm1, float* __restrict__ cm2,
    unsigned* __restrict__ gme1, unsigned* __restrict__ gme2)
{
    if (b == 0) {
        for (int i = t; i < H * D; i += NTHR) cm1[i] = 0.f;
        if (t < D) cm2[t] = 0.f;
        if (t < H) gme1[t] = 0u;
        if (t == 0) gme2[0] = 0u;
    }
    #pragma unroll 1
    for (int it = 0; it < 16; ++it) {              // adj -> bits, 8 adj per thread
        const int tid = it * (NBLK * NTHR) + b * NTHR + t;
        const size_t e0 = (size_t)tid * 8;
        int4 a0 = *(const int4*)&adj[e0];
        int4 a1 = *(const int4*)&adj[e0 + 4];
        unsigned by = (unsigned)(a0.x != 0)        | ((unsigned)(a0.y != 0) << 1)
                    | ((unsigned)(a0.z != 0) << 2) | ((unsigned)(a0.w != 0) << 3)
                    | ((unsigned)(a1.x != 0) << 4) | ((unsigned)(a1.y != 0) << 5)
                    | ((unsigned)(a1.z != 0) << 6) | ((unsigned)(a1.w != 0) << 7);
        unsigned v = by | (__shfl_xor((int)by, 1) << 8);
        v = v | ((unsigned)__shfl_xor((int)v, 2) << 16);
        if ((t & 3) == 0) bits32[tid >> 2] = v;
    }
    #pragma unroll 1
    for (int it = 0; it < 4; ++it) {               // x -> f16
        const size_t i4 = ((size_t)it * (NBLK * NTHR) + b * NTHR + t) * 4;
        float4 v = *(const float4*)&x[i4];
        ushort4 o;
        o.x = (unsigned short)f2h(v.x); o.y = (unsigned short)f2h(v.y);
        o.z = (unsigned short)f2h(v.z); o.w = (unsigned short)f2h(v.w);
        *(ushort4*)&Xbf[i4] = o;
    }
    #pragma unroll 1
    for (int it = 0; it < 2; ++it) {               // W -> fragment layout
        const size_t idx = (size_t)it * (NBLK * NTHR) + b * NTHR + t;
        const int d = idx & 63;
        const int k = (int)(idx >> 6) & 511;
        const int h = (int)(idx >> 15);
        WF[(((size_t)h * 64 + (k >> 3)) * 64 + d) * 8 + (k & 7)] = f2h(W[idx]);
    }
    {
        const int idx = b * NTHR + t;              // W_o
        if (idx < FDIM * D) {
            const int d = idx & 63;
            const int k = idx >> 6;
            WoF[(((size_t)(k >> 3)) * 64 + d) * 8 + (k & 7)] = f2h(Wo[idx]);
        }
    }
}

// ---- gemm block: 2 waves x 16 rows = 32 rows, [32,512]@[512,64] + fused stats
__device__ __forceinline__ void gemm_block(
    const short* __restrict__ Xsrc, const short* __restrict__ WFh,
    const float* __restrict__ av, const float* __restrict__ bv,
    short* __restrict__ WBh, float* __restrict__ fsh, float* __restrict__ fdh,
    unsigned* __restrict__ gmaxp, float* __restrict__ cmh,
    int i0, int t, Smem& sm)
{
    const int w = t >> 6, lane = t & 63;
    const int li = lane & 15, quad = lane >> 4, k0 = quad * 8;
    const int row_a = i0 + w * 16 + li;
    const short* __restrict__ Xr = Xsrc + (size_t)row_a * FDIM;

    f32x4 c0 = {0.f, 0.f, 0.f, 0.f}, c1 = c0, c2 = c0, c3 = c0;
    #pragma unroll 4
    for (int kt = 0; kt < FDIM; kt += 32) {
        f16x8 a = __builtin_bit_cast(f16x8, *(const bf16x8*)&Xr[kt + k0]);
        const short* bb = WFh + (size_t)((kt >> 3) + quad) * (D * 8) + li * 8;
        f16x8 b0 = __builtin_bit_cast(f16x8, *(const bf16x8*)(bb));
        f16x8 b1 = __builtin_bit_cast(f16x8, *(const bf16x8*)(bb + 128));
        f16x8 b2 = __builtin_bit_cast(f16x8, *(const bf16x8*)(bb + 256));
        f16x8 b3 = __builtin_bit_cast(f16x8, *(const bf16x8*)(bb + 384));
        c0 = __builtin_amdgcn_mfma_f32_16x16x32_f16(a, b0, c0, 0, 0, 0);
        c1 = __builtin_amdgcn_mfma_f32_16x16x32_f16(a, b1, c1, 0, 0, 0);
        c2 = __builtin_amdgcn_mfma_f32_16x16x32_f16(a, b2, c2, 0, 0, 0);
        c3 = __builtin_amdgcn_mfma_f32_16x16x32_f16(a, b3, c3, 0, 0, 0);
    }
    float av4[4], bv4[4];
    #pragma unroll
    for (int t4 = 0; t4 < 4; ++t4) {
        av4[t4] = av[t4 * 16 + li];
        bv4[t4] = bv[t4 * 16 + li];
    }
    float tiles[4][4];
    #pragma unroll
    for (int r = 0; r < 4; ++r) { tiles[0][r] = c0[r]; tiles[1][r] = c1[r]; tiles[2][r] = c2[r]; tiles[3][r] = c3[r]; }

    float fdmax = -INFINITY;
    float s4[4] = {0.f, 0.f, 0.f, 0.f};
    #pragma unroll
    for (int r = 0; r < 4; ++r) {
        const int row = i0 + w * 16 + quad * 4 + r;
        float pa = 0.f, pb = 0.f;
        #pragma unroll
        for (int t4 = 0; t4 < 4; ++t4) {
            const float v = tiles[t4][r];
            const int d = t4 * 16 + li;
            WBh[((size_t)(row >> 3)) * (D * 8) + d * 8 + (row & 7)] = f2h(v);
            pa += v * av4[t4];
            pb += v * bv4[t4];
            s4[t4] += v;
        }
        #pragma unroll
        for (int off = 1; off < 16; off <<= 1) {
            pa += __shfl_xor(pa, off);
            pb += __shfl_xor(pb, off);
        }
        if (li == 0) {
            fsh[row] = pa;
            fdh[row] = pb;
        }
        fdmax = fmaxf(fdmax, pb);
    }
    fdmax = fmaxf(fdmax, __shfl_xor(fdmax, 16));
    fdmax = fmaxf(fdmax, __shfl_xor(fdmax, 32));
    if (lane == 0) sm.g.red[w] = fdmax;
    #pragma unroll
    for (int t4 = 0; t4 < 4; ++t4) {
        s4[t4] += __shfl_xor(s4[t4], 16);
        s4[t4] += __shfl_xor(s4[t4], 32);
    }
    if (quad == 0)
        #pragma unroll
        for (int t4 = 0; t4 < 4; ++t4) sm.g.csum[w * 64 + t4 * 16 + li] = s4[t4];
    __syncthreads();
    if (t == 0)
        atomicMax(gmaxp, fenc(fmaxf(sm.g.red[0], sm.g.red[1])));
    if (t < 64)
        atomicAdd(&cmh[t], (sm.g.csum[t] + sm.g.csum[64 + t]) * (1.f / (float)N_NODES));
}

// ---- accum slab: 2 waves x 64 rows (F=4), kslab j's, DMA-staged, 2-phase sync
__device__ __forceinline__ void accum_slab(
    const unsigned int* __restrict__ bits32, const short* __restrict__ Bh,
    const float* __restrict__ fsh, const float* __restrict__ fdh,
    float gm, int i0, int k_beg, int kslab,
    short* __restrict__ num, float* __restrict__ den, size_t so,
    int t, Smem& sm)
{
    const int w = t >> 6, lane = t & 63;
    const int li = lane & 15, quad = lane >> 4, k0 = quad * 8;
    const int ntile = kslab / 128;

    auto stage = [&](int buf, int jtile) {
        const short* src = Bh + (size_t)(jtile >> 3) * (D * 8);
        #pragma unroll
        for (int p = 0; p < 8; ++p)
            gl2lds16(src + (size_t)(p * 128 + t) * 8, &sm.a.Bt[buf][(p * 128 + t) * 8]);
    };

    int bito[4];
    #pragma unroll
    for (int f = 0; f < 4; ++f)
        bito[f] = (i0 + w * 64 + f * 16 + li) * (NWORDS * 2);
    stage(0, k_beg);
    for (int jj = t * 2; jj < kslab; jj += 2 * NTHR) {     // EG table, whole slab
        float2 f2 = *(const float2*)&fdh[k_beg + jj];
        f16x2 ep = {(_Float16)__expf(f2.x - gm), (_Float16)__expf(f2.y - gm)};
        f16x2 gp = {(_Float16)__expf(0.2f * (f2.x - gm)),
                    (_Float16)__expf(0.2f * (f2.y - gm))};
        *(f16x2*)&sm.a.Esh[jj] = ep;
        *(f16x2*)&sm.a.Gsh[jj] = gp;
    }
    f16x2 Rp[4];
    #pragma unroll
    for (int f = 0; f < 4; ++f) {
        const float rv = __expf(-0.8f * (fsh[i0 + w * 64 + f * 16 + li] + gm));
        const _Float16 rh = (_Float16)rv;
        Rp[f] = (f16x2){rh, rh};
    }

    f32x4 acc[4][4], c5[4];
    #pragma unroll
    for (int f = 0; f < 4; ++f) {
        #pragma unroll
        for (int q = 0; q < 4; ++q) acc[f][q] = (f32x4){0.f, 0.f, 0.f, 0.f};
        c5[f] = (f32x4){0.f, 0.f, 0.f, 0.f};
    }
    bf16x8 ones_;
    #pragma unroll
    for (int j = 0; j < 8; ++j) ones_[j] = (short)0x3C00;    // f16 1.0
    const f16x8 ones = __builtin_bit_cast(f16x8, ones_);

    __syncthreads();                    // stage(0) + EG landed

    for (int tile = 0; tile < ntile; ++tile) {
        const int jt = k_beg + tile * 128;
        if (tile + 1 < ntile) stage((tile + 1) & 1, jt + 128);

        uint4 bw[4];
        #pragma unroll
        for (int f = 0; f < 4; ++f)
            bw[f] = *(const uint4*)&bits32[(size_t)bito[f] + (jt >> 5)];

        const short* Bl = sm.a.Bt[tile & 1];
        const short* Ee = sm.a.Esh + tile * 128;
        const short* Gg = sm.a.Gsh + tile * 128;
        #pragma unroll
        for (int s = 0; s < 4; ++s) {
            const uint4 Eu = *(const uint4*)&Ee[s * 32 + k0];   // 8 f16 per quad
            const uint4 Gu = *(const uint4*)&Gg[s * 32 + k0];
            f16x2 Ep[4] = {bcH(Eu.x), bcH(Eu.y), bcH(Eu.z), bcH(Eu.w)};
            f16x2 Gp[4] = {bcH(Gu.x), bcH(Gu.y), bcH(Gu.z), bcH(Gu.w)};
            const short* bb = Bl + (size_t)((s * 4 + quad) * 64 + li) * 8;
            f16x8 b0 = __builtin_bit_cast(f16x8, *(const bf16x8*)(bb));
            f16x8 b1 = __builtin_bit_cast(f16x8, *(const bf16x8*)(bb + 128));
            f16x8 b2 = __builtin_bit_cast(f16x8, *(const bf16x8*)(bb + 256));
            f16x8 b3 = __builtin_bit_cast(f16x8, *(const bf16x8*)(bb + 384));
            #pragma unroll
            for (int f = 0; f < 4; ++f) {
                const unsigned int wsel = (s == 0) ? bw[f].x : (s == 1) ? bw[f].y
                                        : (s == 2) ? bw[f].z : bw[f].w;
                const unsigned int byt = (wsel >> k0) & 0xFFu;
                u32x4 au;
                #pragma unroll
                for (int d2 = 0; d2 < 4; ++d2) {
                    const unsigned mw = (unsigned)__builtin_amdgcn_perm(
                        (unsigned)sext_bit(byt, 2 * d2 + 1),
                        (unsigned)sext_bit(byt, 2 * d2), 0x05040100u);
                    const f16x2 tv = Gp[d2] * Rp[f];                        // v_pk_mul_f16
                    const f16x2 pv = __builtin_elementwise_max(Ep[d2], tv); // v_pk_max_f16
                    au[d2] = __builtin_bit_cast(unsigned, pv) & mw;
                }
                const f16x8 a = __builtin_bit_cast(f16x8, au);
                __builtin_amdgcn_s_setprio(1);
                acc[f][0] = __builtin_amdgcn_mfma_f32_16x16x32_f16(a, b0, acc[f][0], 0, 0, 0);
                acc[f][1] = __builtin_amdgcn_mfma_f32_16x16x32_f16(a, b1, acc[f][1], 0, 0, 0);
                acc[f][2] = __builtin_amdgcn_mfma_f32_16x16x32_f16(a, b2, acc[f][2], 0, 0, 0);
                acc[f][3] = __builtin_amdgcn_mfma_f32_16x16x32_f16(a, b3, acc[f][3], 0, 0, 0);
                c5[f]     = __builtin_amdgcn_mfma_f32_16x16x32_f16(a, ones, c5[f], 0, 0, 0);
                __builtin_amdgcn_s_setprio(0);
            }
        }
        __syncthreads();                // stage(t+1) landed, Bt[tile&1] reusable
    }

    #pragma unroll
    for (int f = 0; f < 4; ++f) {
        #pragma unroll
        for (int t4 = 0; t4 < 4; ++t4)
            #pragma unroll
            for (int r = 0; r < 4; ++r) {
                const int row = i0 + w * 64 + f * 16 + quad * 4 + r;
                num[(so * N_NODES + row) * D + t4 * 16 + li] = f2h(acc[f][t4][r]);
            }
        if (li == 0)
            #pragma unroll
            for (int r = 0; r < 4; ++r)
                den[so * N_NODES + i0 + w * 64 + f * 16 + quad * 4 + r] = c5[f][r];
    }
}

// ---- P3: layer-1 combine (b in [0,1024) x 128 thr remapped to old 512x256)
__device__ __forceinline__ void phase_post1(int b, int t,
    const short* __restrict__ num, const float* __restrict__ den,
    const float* __restrict__ colmean, short* __restrict__ hcat)
{
    const int ob = b >> 1;
    const int ot = ((b & 1) << 7) | t;
    const int h  = ob >> 6;
    const int row = (ob & 63) * 64 + (ot >> 2);
    const int cb  = (ot & 3) * 16;
    const size_t HN = (size_t)H * N_NODES;
    const size_t r0 = (size_t)h * N_NODES + row;
    float dsum = 0.f;
    #pragma unroll
    for (int s = 0; s < S1; ++s) dsum += den[s * HN + r0];
    const bool  uni  = !(dsum > 0.f);
    const float linv = uni ? 0.f : 1.f / dsum;
    #pragma unroll
    for (int c = 0; c < 4; ++c) {
        const int col = cb + c * 4;
        float4 v = {0.f, 0.f, 0.f, 0.f};
        #pragma unroll
        for (int s = 0; s < S1; ++s) {
            ushort4 a = *(const ushort4*)&num[(s * HN + r0) * D + col];
            v.x += h2f(a.x); v.y += h2f(a.y); v.z += h2f(a.z); v.w += h2f(a.w);
        }
        v.x *= linv; v.y *= linv; v.z *= linv; v.w *= linv;
        if (uni) v = *(const float4*)&colmean[h * D + col];
        v.x = v.x > 0.f ? v.x : __expf(v.x) - 1.f;
        v.y = v.y > 0.f ? v.y : __expf(v.y) - 1.f;
        v.z = v.z > 0.f ? v.z : __expf(v.z) - 1.f;
        v.w = v.w > 0.f ? v.w : __expf(v.w) - 1.f;
        ushort4 o;
        o.x = (unsigned short)f2h(v.x); o.y = (unsigned short)f2h(v.y);
        o.z = (unsigned short)f2h(v.z); o.w = (unsigned short)f2h(v.w);
        *(ushort4*)&hcat[(size_t)row * (H * D) + h * D + col] = o;
    }
}

// ---- P6: layer-2 combine + ELU + log_softmax (2 rows per wave)
__device__ __forceinline__ void phase_lsm(int b, int t,
    const short* __restrict__ num, const float* __restrict__ den,
    const float* __restrict__ cm, float* __restrict__ out)
{
    const int gw = b * 2 + (t >> 6);
    const int lane = t & 63;
    #pragma unroll
    for (int rr = 0; rr < 2; ++rr) {
        const int n = gw * 2 + rr;
        float v = 0.f, ds = 0.f;
        #pragma unroll
        for (int s = 0; s < S2; ++s)
            v += h2f((unsigned short)num[((size_t)s * N_NODES + n) * D + lane]);
        #pragma unroll
        for (int s = 0; s < S2; ++s) ds += den[(size_t)s * N_NODES + n];
        v = (ds > 0.f) ? v / ds : cm[lane];
        v = v > 0.f ? v : __expf(v) - 1.f;
        float mx = v;
        #pragma unroll
        for (int off = 32; off > 0; off >>= 1) mx = fmaxf(mx, __shfl_xor(mx, off));
        float ex = __expf(v - mx);
        float sum = ex;
        #pragma unroll
        for (int off = 32; off > 0; off >>= 1) sum += __shfl_xor(sum, off);
        out[(size_t)n * D + lane] = (v - mx) - __logf(sum);
    }
}

// ================================================================ mega kernel (cooperative)
__global__ void __launch_bounds__(NTHR, 2) k_mega(
    const float* x, const int* adj, const float* W, const float* Wo,
    const float* a_src, const float* a_dst, const float* ao_src, const float* ao_dst,
    unsigned* bits32, short* Xbf, short* WF1, short* WoF,
    short* WhB, float* fs1, float* fd1, unsigned* gme1, float* cm1,
    short* num1, float* den1, short* hcat,
    short* WhoB, float* fs2, float* fd2, unsigned* gme2, float* cm2,
    short* num2, float* den2, float* out)
{
    __shared__ Smem sm;
    cg::grid_group grid = cg::this_grid();
    const int b = blockIdx.x, t = threadIdx.x;

    // P0: preprocessing
    phase_pre(b, t, adj, x, W, Wo, bits32, Xbf, WF1, WoF, cm1, cm2, gme1, gme2);
    grid.sync();

    // P1: layer-1 GEMM (1024 = 128 rowblocks x 8 heads)
    {
        const int h = b >> 7, rb = b & 127;
        gemm_block(Xbf, WF1 + (size_t)h * 64 * D * 8, a_src + h * D, a_dst + h * D,
                   WhB + (size_t)h * (N_NODES / 8) * (D * 8),
                   fs1 + (size_t)h * N_NODES, fd1 + (size_t)h * N_NODES,
                   gme1 + h, cm1 + h * D, rb * 32, t, sm);
    }
    grid.sync();

    // P2: layer-1 attention slabs (1024 = 32 rowblocks x 8 heads x 4 slabs)
    {
        const int rb = b & 31, h = (b >> 5) & 7, slab = b >> 8;
        accum_slab(bits32, WhB + (size_t)h * (N_NODES / 8) * (D * 8),
                   fs1 + (size_t)h * N_NODES, fd1 + (size_t)h * N_NODES,
                   fdec(gme1[h]), rb * 128, slab * (N_NODES / S1), N_NODES / S1,
                   num1, den1, (size_t)slab * H + h, t, sm);
    }
    grid.sync();

    // P3: layer-1 combine -> hcat
    phase_post1(b, t, num1, den1, cm1, hcat);
    grid.sync();

    // P4: layer-2 GEMM (blocks 0..127; rest idle to the sync)
    if (b < 128)
        gemm_block(hcat, WoF, ao_src, ao_dst, WhoB, fs2, fd2, gme2, cm2,
                   b * 32, t, sm);
    grid.sync();

    // P5: layer-2 attention slabs (1024 = 32 rowblocks x 32 slabs, ntile=1)
    {
        const int rb = b & 31, slab = b >> 5;
        accum_slab(bits32, WhoB, fs2, fd2, fdec(gme2[0]),
                   rb * 128, slab * (N_NODES / S2), N_NODES / S2,
                   num2, den2, (size_t)slab, t, sm);
    }
    grid.sync();

    // P6: combine + ELU + log_softmax -> out
    phase_lsm(b, t, num2, den2, cm2, out);
}

// ================================================================ fallback wrappers (plain launches)
__global__ void __launch_bounds__(NTHR, 2) g_pre(
    const float* x, const int* adj, const float* W, const float* Wo,
    unsigned* bits32, short* Xbf, short* WF1, short* WoF,
    float* cm1, float* cm2, unsigned* gme1, unsigned* gme2) {
    phase_pre(blockIdx.x, threadIdx.x, adj, x, W, Wo, bits32, Xbf, WF1, WoF,
              cm1, cm2, gme1, gme2);
}
__global__ void __launch_bounds__(NTHR, 2) g_gemm1(
    const short* Xbf, const short* WF1, const float* a_src, const float* a_dst,
    short* WhB, float* fs1, float* fd1, unsigned* gme1, float* cm1) {
    __shared__ Smem sm;
    const int b = blockIdx.x, h = b >> 7, rb = b & 127;
    gemm_block(Xbf, WF1 + (size_t)h * 64 * D * 8, a_src + h * D, a_dst + h * D,
               WhB + (size_t)h * (N_NODES / 8) * (D * 8),
               fs1 + (size_t)h * N_NODES, fd1 + (size_t)h * N_NODES,
               gme1 + h, cm1 + h * D, rb * 32, threadIdx.x, sm);
}
__global__ void __launch_bounds__(NTHR, 2) g_accum1(
    const unsigned* bits32, const short* WhB, const float* fs1, const float* fd1,
    const unsigned* gme1, short* num1, float* den1) {
    __shared__ Smem sm;
    const int b = blockIdx.x, rb = b & 31, h = (b >> 5) & 7, slab = b >> 8;
    accum_slab(bits32, WhB + (size_t)h * (N_NODES / 8) * (D * 8),
               fs1 + (size_t)h * N_NODES, fd1 + (size_t)h * N_NODES,
               fdec(gme1[h]), rb * 128, slab * (N_NODES / S1), N_NODES / S1,
               num1, den1, (size_t)slab * H + h, threadIdx.x, sm);
}
__global__ void __launch_bounds__(NTHR, 2) g_post1(
    const short* num1, const float* den1, const float* cm1, short* hcat) {
    phase_post1(blockIdx.x, threadIdx.x, num1, den1, cm1, hcat);
}
__global__ void __launch_bounds__(NTHR, 2) g_gemm2(
    const short* hcat, const short* WoF, const float* ao_src, const float* ao_dst,
    short* WhoB, float* fs2, float* fd2, unsigned* gme2, float* cm2) {
    __shared__ Smem sm;
    gemm_block(hcat, WoF, ao_src, ao_dst, WhoB, fs2, fd2, gme2, cm2,
               blockIdx.x * 32, threadIdx.x, sm);
}
__global__ void __launch_bounds__(NTHR, 2) g_accum2(
    const unsigned* bits32, const short* WhoB, const float* fs2, const float* fd2,
    const unsigned* gme2, short* num2, float* den2) {
    __shared__ Smem sm;
    const int b = blockIdx.x, rb = b & 31, slab = b >> 5;
    accum_slab(bits32, WhoB, fs2, fd2, fdec(gme2[0]),
               rb * 128, slab * (N_NODES / S2), N_NODES / S2,
               num2, den2, (size_t)slab, threadIdx.x, sm);
}
__global__ void __launch_bounds__(NTHR, 2) g_lsm(
    const short* num2, const float* den2, const float* cm2, float* out) {
    phase_lsm(blockIdx.x, threadIdx.x, num2, den2, cm2, out);
}

// ----------------------------------------------------------------
extern "C" void kernel_launch(void* const* d_in, const int* in_sizes, int n_in,
                              void* d_out, int out_size, void* d_ws, size_t ws_size,
                              hipStream_t stream) {
    const float* x      = (const float*)d_in[0];
    const int*   adj    = (const int*)d_in[1];
    const float* W      = (const float*)d_in[2];
    const float* a_src  = (const float*)d_in[3];
    const float* a_dst  = (const float*)d_in[4];
    const float* W_o    = (const float*)d_in[5];
    const float* ao_src = (const float*)d_in[6];
    const float* ao_dst = (const float*)d_in[7];
    float* out = (float*)d_out;

    char* wsp = (char*)d_ws;
    size_t off = 0;
    auto alloc = [&](size_t bytes) -> void* {
        void* p = wsp + off;
        off += (bytes + 255) & ~(size_t)255;
        return p;
    };
    unsigned* adj_bits = (unsigned*)alloc((size_t)N_NODES * NWORDS * 8);
    short*    Xbf   = (short*)alloc((size_t)N_NODES * FDIM * 2);
    short*    WF1   = (short*)alloc((size_t)H * 64 * D * 8 * 2);
    short*    WoF   = (short*)alloc((size_t)64 * D * 8 * 2);
    short*    WhB   = (short*)alloc((size_t)H * N_NODES * D * 2);
    float*    fs1   = (float*)alloc((size_t)H * N_NODES * 4);
    float*    fd1   = (float*)alloc((size_t)H * N_NODES * 4);
    unsigned* gme1  = (unsigned*)alloc((size_t)H * 4);
    float*    cm1   = (float*)alloc((size_t)H * D * 4);
    short*    num1  = (short*)alloc((size_t)S1 * H * N_NODES * D * 2);
    float*    den1  = (float*)alloc((size_t)S1 * H * N_NODES * 4);
    short*    hcat  = (short*)alloc((size_t)N_NODES * H * D * 2);
    short*    WhoB  = (short*)alloc((size_t)N_NODES * D * 2);
    float*    fs2   = (float*)alloc((size_t)N_NODES * 4);
    float*    fd2   = (float*)alloc((size_t)N_NODES * 4);
    unsigned* gme2  = (unsigned*)alloc(4);
    float*    cm2   = (float*)alloc((size_t)D * 4);
    short*    num2  = (short*)alloc((size_t)S2 * N_NODES * D * 2);
    float*    den2  = (float*)alloc((size_t)S2 * N_NODES * 4);

    void* kargs[] = {
        (void*)&x, (void*)&adj, (void*)&W, (void*)&W_o,
        (void*)&a_src, (void*)&a_dst, (void*)&ao_src, (void*)&ao_dst,
        (void*)&adj_bits, (void*)&Xbf, (void*)&WF1, (void*)&WoF,
        (void*)&WhB, (void*)&fs1, (void*)&fd1, (void*)&gme1, (void*)&cm1,
        (void*)&num1, (void*)&den1, (void*)&hcat,
        (void*)&WhoB, (void*)&fs2, (void*)&fd2, (void*)&gme2, (void*)&cm2,
        (void*)&num2, (void*)&den2, (void*)&out };

    hipError_t cerr = hipLaunchCooperativeKernel(
        (const void*)k_mega, dim3(NBLK), dim3(NTHR), kargs, 0u, stream);

    if (cerr != hipSuccess) {
        // fallback: identical phases as 7 plain launches (R3-parity path)
        g_pre   <<<dim3(NBLK), dim3(NTHR), 0, stream>>>(x, adj, W, W_o, adj_bits, Xbf,
                                                        WF1, WoF, cm1, cm2, gme1, gme2);
        g_gemm1 <<<dim3(NBLK), dim3(NTHR), 0, stream>>>(Xbf, WF1, a_src, a_dst,
                                                        WhB, fs1, fd1, gme1, cm1);
        g_accum1<<<dim3(NBLK), dim3(NTHR), 0, stream>>>(adj_bits, WhB, fs1, fd1, gme1,
                                                        num1, den1);
        g_post1 <<<dim3(NBLK), dim3(NTHR), 0, stream>>>(num1, den1, cm1, hcat);
        g_gemm2 <<<dim3(128),  dim3(NTHR), 0, stream>>>(hcat, WoF, ao_src, ao_dst,
                                                        WhoB, fs2, fd2, gme2, cm2);
        g_accum2<<<dim3(NBLK), dim3(NTHR), 0, stream>>>(adj_bits, WhoB, fs2, fd2, gme2,
                                                        num2, den2);
        g_lsm   <<<dim3(NBLK), dim3(NTHR), 0, stream>>>(num2, den2, cm2, out);
    }
}

// Round 9
// 505.550 us; speedup vs baseline: 1.8335x; 1.8335x over previous
//
#include <hip/hip_runtime.h>
#include <hip/hip_bf16.h>
#include <math.h>

#define N_NODES 4096
#define FDIM 512            // K of both GEMMs (F_in = H*D = 512)
#define D 64
#define H 8
#define NWORDS (N_NODES / 64)
#define S1 4                // layer-1 j-slabs (32 rb x 8 h x 4 = 1024 blocks)
#define S2 32               // layer-2 j-slabs (32 rb x 32 = 1024 blocks, ntile=1)
#define NTHR 128

typedef __attribute__((ext_vector_type(8))) short bf16x8;      // raw 16B of halfwords
typedef __attribute__((ext_vector_type(4))) float f32x4;
typedef __attribute__((ext_vector_type(8))) _Float16 f16x8;    // MFMA f16 operand
typedef __attribute__((ext_vector_type(2))) _Float16 f16x2;    // packed-pair math
typedef __attribute__((ext_vector_type(4))) unsigned int u32x4;

__device__ inline short f2h(float x) {
    _Float16 h = (_Float16)x;
    return __builtin_bit_cast(short, h);
}
__device__ inline float h2f(unsigned short u) {
    return (float)__builtin_bit_cast(_Float16, u);
}
__device__ inline f16x2 bcH(unsigned int u) { return __builtin_bit_cast(f16x2, u); }

__device__ inline int sext_bit(unsigned int v, int j) {        // all-ones iff bit j set
#if defined(__has_builtin) && __has_builtin(__builtin_amdgcn_sbfe)
    return __builtin_amdgcn_sbfe((int)v, j, 1);
#else
    return ((int)(v << (31 - j))) >> 31;
#endif
}

// monotonic float<->uint encoding so unsigned atomicMax == float max
__device__ inline unsigned fenc(float f) {
    unsigned u = __builtin_bit_cast(unsigned, f);
    return (u & 0x80000000u) ? ~u : (u | 0x80000000u);
}
__device__ inline float fdec(unsigned e) {
    unsigned u = (e & 0x80000000u) ? (e & 0x7FFFFFFFu) : ~e;
    return __builtin_bit_cast(float, u);
}

// async global->LDS 16B copy (DMA). LDS dst must be wave-uniform base + lane*16.
__device__ inline void gl2lds16(const void* g, void* l) {
#if defined(__has_builtin) && __has_builtin(__builtin_amdgcn_global_load_lds)
    __builtin_amdgcn_global_load_lds(
        (const __attribute__((address_space(1))) unsigned int*)g,
        (__attribute__((address_space(3))) unsigned int*)l, 16, 0, 0);
#else
    *(uint4*)l = *(const uint4*)g;
#endif
}

// per-block shared scratch, phase-sequential reuse (36,864 B -> 4 blocks/CU)
union Smem {
    struct { short Bt[2][8192]; short Esh[1024]; short Gsh[1024]; } a;  // accum phase
    struct { float csum[128]; float red[2]; } g;                        // gemm finisher
    struct { float dsum[128]; } p;                                      // combine finisher
};

// ---------------------------------------------------------------- fused preprocessing (proven R0-R7)
// band 0: zero cm/gmax/counters; bands: adj->bits | X->f16 | W | W_o
#define NB_BITS (N_NODES * N_NODES / 2048)
#define NB_X    (N_NODES * FDIM / 1024)
#define NB_W    (H * FDIM * D / 256)
#define NB_WO   (FDIM * D / 256)
__global__ void k_pre(const int* __restrict__ adj, const float* __restrict__ x,
                      const float* __restrict__ W, const float* __restrict__ Wo,
                      unsigned int* __restrict__ bits32, short* __restrict__ Xbf,
                      short* __restrict__ WF, short* __restrict__ WoF,
                      float* __restrict__ cm1, float* __restrict__ cm2,
                      unsigned* __restrict__ gmaxe1, unsigned* __restrict__ gmaxe2,
                      int* __restrict__ cnt) {
    const int b = blockIdx.x, t = threadIdx.x;
    if (b == 0) {
        for (int i = t; i < H * D; i += 256) cm1[i] = 0.f;
        if (t < D) cm2[t] = 0.f;
        if (t < H) gmaxe1[t] = 0u;
        if (t == 0) gmaxe2[0] = 0u;
        for (int i = t; i < 320; i += 256) cnt[i] = 0;   // finisher tickets
        return;
    }
    if (b < 1 + NB_BITS) {
        const int tid  = (b - 1) * 256 + t;     // one byte (8 adj) per thread
        const size_t e0 = (size_t)tid * 8;
        int4 a0 = *(const int4*)&adj[e0];
        int4 a1 = *(const int4*)&adj[e0 + 4];
        unsigned by = (unsigned)(a0.x != 0)       | ((unsigned)(a0.y != 0) << 1)
                    | ((unsigned)(a0.z != 0) << 2) | ((unsigned)(a0.w != 0) << 3)
                    | ((unsigned)(a1.x != 0) << 4) | ((unsigned)(a1.y != 0) << 5)
                    | ((unsigned)(a1.z != 0) << 6) | ((unsigned)(a1.w != 0) << 7);
        unsigned v = by | (__shfl_xor((int)by, 1) << 8);
        v = v | ((unsigned)__shfl_xor((int)v, 2) << 16);
        if ((t & 3) == 0) bits32[tid >> 2] = v;
        return;
    }
    if (b < 1 + NB_BITS + NB_X) {
        const size_t i4 = ((size_t)(b - 1 - NB_BITS) * 256 + t) * 4;
        float4 v = *(const float4*)&x[i4];
        ushort4 o;
        o.x = (unsigned short)f2h(v.x); o.y = (unsigned short)f2h(v.y);
        o.z = (unsigned short)f2h(v.z); o.w = (unsigned short)f2h(v.w);
        *(ushort4*)&Xbf[i4] = o;
        return;
    }
    if (b < 1 + NB_BITS + NB_X + NB_W) {
        const size_t idx = (size_t)(b - 1 - NB_BITS - NB_X) * 256 + t;   // (h*512+k)*64+d
        const int d = idx & 63;
        const int k = (int)(idx >> 6) & 511;
        const int h = (int)(idx >> 15);
        WF[(((size_t)h * 64 + (k >> 3)) * 64 + d) * 8 + (k & 7)] = f2h(W[idx]);
        return;
    }
    {
        const size_t idx = (size_t)(b - 1 - NB_BITS - NB_X - NB_W) * 256 + t;  // k*64+d
        const int d = idx & 63;
        const int k = (int)(idx >> 6);
        WoF[(((size_t)(k >> 3)) * 64 + d) * 8 + (k & 7)] = f2h(Wo[idx]);
    }
}

// ---------------------------------------------------------------- MFMA GEMM layer-1 (proven R0-R3, 256 thr)
__global__ void __launch_bounds__(256) k_gemm(
    const short* __restrict__ Xbf, const short* __restrict__ WF,
    const float* __restrict__ av, const float* __restrict__ bv,
    short* __restrict__ WBout, float* __restrict__ fs, float* __restrict__ fd,
    unsigned* __restrict__ gmaxe, float* __restrict__ cm) {
    const int h  = blockIdx.y;
    const int i0 = blockIdx.x * 64;
    const int t = threadIdx.x, w = t >> 6, lane = t & 63;
    const int li = lane & 15, quad = lane >> 4, k0 = quad * 8;
    const int row_a = i0 + w * 16 + li;
    const short* __restrict__ Xr  = Xbf + (size_t)row_a * FDIM;
    const short* __restrict__ WFh = WF + (size_t)h * 64 * D * 8;

    f32x4 c0 = {0.f, 0.f, 0.f, 0.f}, c1 = c0, c2 = c0, c3 = c0;
    #pragma unroll 4
    for (int kt = 0; kt < FDIM; kt += 32) {
        f16x8 a = __builtin_bit_cast(f16x8, *(const bf16x8*)&Xr[kt + k0]);
        const short* bb = WFh + (size_t)((kt >> 3) + quad) * (D * 8) + li * 8;
        f16x8 b0 = __builtin_bit_cast(f16x8, *(const bf16x8*)(bb));
        f16x8 b1 = __builtin_bit_cast(f16x8, *(const bf16x8*)(bb + 128));
        f16x8 b2 = __builtin_bit_cast(f16x8, *(const bf16x8*)(bb + 256));
        f16x8 b3 = __builtin_bit_cast(f16x8, *(const bf16x8*)(bb + 384));
        c0 = __builtin_amdgcn_mfma_f32_16x16x32_f16(a, b0, c0, 0, 0, 0);
        c1 = __builtin_amdgcn_mfma_f32_16x16x32_f16(a, b1, c1, 0, 0, 0);
        c2 = __builtin_amdgcn_mfma_f32_16x16x32_f16(a, b2, c2, 0, 0, 0);
        c3 = __builtin_amdgcn_mfma_f32_16x16x32_f16(a, b3, c3, 0, 0, 0);
    }
    float av4[4], bv4[4];
    #pragma unroll
    for (int t4 = 0; t4 < 4; ++t4) {
        av4[t4] = av[h * D + t4 * 16 + li];
        bv4[t4] = bv[h * D + t4 * 16 + li];
    }
    float tiles[4][4];
    #pragma unroll
    for (int r = 0; r < 4; ++r) { tiles[0][r] = c0[r]; tiles[1][r] = c1[r]; tiles[2][r] = c2[r]; tiles[3][r] = c3[r]; }

    __shared__ float csum[4][64];
    __shared__ float red[4];
    float fdmax = -INFINITY;
    float s4[4] = {0.f, 0.f, 0.f, 0.f};

    #pragma unroll
    for (int r = 0; r < 4; ++r) {
        const int row = i0 + w * 16 + quad * 4 + r;
        float pa = 0.f, pb = 0.f;
        #pragma unroll
        for (int t4 = 0; t4 < 4; ++t4) {
            const float v = tiles[t4][r];
            const int d = t4 * 16 + li;
            WBout[((size_t)h * (N_NODES / 8) + (row >> 3)) * (D * 8) + d * 8 + (row & 7)] = f2h(v);
            pa += v * av4[t4];
            pb += v * bv4[t4];
            s4[t4] += v;
        }
        #pragma unroll
        for (int off = 1; off < 16; off <<= 1) {
            pa += __shfl_xor(pa, off);
            pb += __shfl_xor(pb, off);
        }
        if (li == 0) {
            fs[(size_t)h * N_NODES + row] = pa;
            fd[(size_t)h * N_NODES + row] = pb;
        }
        fdmax = fmaxf(fdmax, pb);
    }
    fdmax = fmaxf(fdmax, __shfl_xor(fdmax, 16));
    fdmax = fmaxf(fdmax, __shfl_xor(fdmax, 32));
    if (lane == 0) red[w] = fdmax;
    #pragma unroll
    for (int t4 = 0; t4 < 4; ++t4) {
        s4[t4] += __shfl_xor(s4[t4], 16);
        s4[t4] += __shfl_xor(s4[t4], 32);
    }
    if (quad == 0)
        #pragma unroll
        for (int t4 = 0; t4 < 4; ++t4) csum[w][t4 * 16 + li] = s4[t4];
    __syncthreads();
    if (t == 0)
        atomicMax(gmaxe + h, fenc(fmaxf(fmaxf(red[0], red[1]), fmaxf(red[2], red[3]))));
    if (t < 64)
        atomicAdd(&cm[h * D + t],
                  (csum[0][t] + csum[1][t] + csum[2][t] + csum[3][t]) * (1.f / (float)N_NODES));
}

// ---------------------------------------------------------------- accum slab body (proven R3/R8, 128 thr, F=4)
__device__ __forceinline__ void accum_slab(
    const unsigned int* __restrict__ bits32, const short* __restrict__ Bh,
    const float* __restrict__ fsh, const float* __restrict__ fdh,
    float gm, int i0, int k_beg, int kslab,
    short* __restrict__ num, float* __restrict__ den, size_t so,
    int t, Smem& sm)
{
    const int w = t >> 6, lane = t & 63;
    const int li = lane & 15, quad = lane >> 4, k0 = quad * 8;
    const int ntile = kslab / 128;

    auto stage = [&](int buf, int jtile) {
        const short* src = Bh + (size_t)(jtile >> 3) * (D * 8);
        #pragma unroll
        for (int p = 0; p < 8; ++p)
            gl2lds16(src + (size_t)(p * 128 + t) * 8, &sm.a.Bt[buf][(p * 128 + t) * 8]);
    };

    int bito[4];
    #pragma unroll
    for (int f = 0; f < 4; ++f)
        bito[f] = (i0 + w * 64 + f * 16 + li) * (NWORDS * 2);
    stage(0, k_beg);
    for (int jj = t * 2; jj < kslab; jj += 2 * NTHR) {     // EG table, whole slab
        float2 f2 = *(const float2*)&fdh[k_beg + jj];
        f16x2 ep = {(_Float16)__expf(f2.x - gm), (_Float16)__expf(f2.y - gm)};
        f16x2 gp = {(_Float16)__expf(0.2f * (f2.x - gm)),
                    (_Float16)__expf(0.2f * (f2.y - gm))};
        *(f16x2*)&sm.a.Esh[jj] = ep;
        *(f16x2*)&sm.a.Gsh[jj] = gp;
    }
    f16x2 Rp[4];
    #pragma unroll
    for (int f = 0; f < 4; ++f) {
        const float rv = __expf(-0.8f * (fsh[i0 + w * 64 + f * 16 + li] + gm));
        const _Float16 rh = (_Float16)rv;
        Rp[f] = (f16x2){rh, rh};
    }

    f32x4 acc[4][4], c5[4];
    #pragma unroll
    for (int f = 0; f < 4; ++f) {
        #pragma unroll
        for (int q = 0; q < 4; ++q) acc[f][q] = (f32x4){0.f, 0.f, 0.f, 0.f};
        c5[f] = (f32x4){0.f, 0.f, 0.f, 0.f};
    }
    bf16x8 ones_;
    #pragma unroll
    for (int j = 0; j < 8; ++j) ones_[j] = (short)0x3C00;    // f16 1.0
    const f16x8 ones = __builtin_bit_cast(f16x8, ones_);

    __syncthreads();                    // stage(0) + EG landed

    for (int tile = 0; tile < ntile; ++tile) {
        const int jt = k_beg + tile * 128;
        if (tile + 1 < ntile) stage((tile + 1) & 1, jt + 128);

        uint4 bw[4];
        #pragma unroll
        for (int f = 0; f < 4; ++f)
            bw[f] = *(const uint4*)&bits32[(size_t)bito[f] + (jt >> 5)];

        const short* Bl = sm.a.Bt[tile & 1];
        const short* Ee = sm.a.Esh + tile * 128;
        const short* Gg = sm.a.Gsh + tile * 128;
        #pragma unroll
        for (int s = 0; s < 4; ++s) {
            const uint4 Eu = *(const uint4*)&Ee[s * 32 + k0];
            const uint4 Gu = *(const uint4*)&Gg[s * 32 + k0];
            f16x2 Ep[4] = {bcH(Eu.x), bcH(Eu.y), bcH(Eu.z), bcH(Eu.w)};
            f16x2 Gp[4] = {bcH(Gu.x), bcH(Gu.y), bcH(Gu.z), bcH(Gu.w)};
            const short* bb = Bl + (size_t)((s * 4 + quad) * 64 + li) * 8;
            f16x8 b0 = __builtin_bit_cast(f16x8, *(const bf16x8*)(bb));
            f16x8 b1 = __builtin_bit_cast(f16x8, *(const bf16x8*)(bb + 128));
            f16x8 b2 = __builtin_bit_cast(f16x8, *(const bf16x8*)(bb + 256));
            f16x8 b3 = __builtin_bit_cast(f16x8, *(const bf16x8*)(bb + 384));
            #pragma unroll
            for (int f = 0; f < 4; ++f) {
                const unsigned int wsel = (s == 0) ? bw[f].x : (s == 1) ? bw[f].y
                                        : (s == 2) ? bw[f].z : bw[f].w;
                const unsigned int byt = (wsel >> k0) & 0xFFu;
                u32x4 au;
                #pragma unroll
                for (int d2 = 0; d2 < 4; ++d2) {
                    const unsigned mw = (unsigned)__builtin_amdgcn_perm(
                        (unsigned)sext_bit(byt, 2 * d2 + 1),
                        (unsigned)sext_bit(byt, 2 * d2), 0x05040100u);
                    const f16x2 tv = Gp[d2] * Rp[f];                        // v_pk_mul_f16
                    const f16x2 pv = __builtin_elementwise_max(Ep[d2], tv); // v_pk_max_f16
                    au[d2] = __builtin_bit_cast(unsigned, pv) & mw;
                }
                const f16x8 a = __builtin_bit_cast(f16x8, au);
                __builtin_amdgcn_s_setprio(1);
                acc[f][0] = __builtin_amdgcn_mfma_f32_16x16x32_f16(a, b0, acc[f][0], 0, 0, 0);
                acc[f][1] = __builtin_amdgcn_mfma_f32_16x16x32_f16(a, b1, acc[f][1], 0, 0, 0);
                acc[f][2] = __builtin_amdgcn_mfma_f32_16x16x32_f16(a, b2, acc[f][2], 0, 0, 0);
                acc[f][3] = __builtin_amdgcn_mfma_f32_16x16x32_f16(a, b3, acc[f][3], 0, 0, 0);
                c5[f]     = __builtin_amdgcn_mfma_f32_16x16x32_f16(a, ones, c5[f], 0, 0, 0);
                __builtin_amdgcn_s_setprio(0);
            }
        }
        __syncthreads();
    }

    #pragma unroll
    for (int f = 0; f < 4; ++f) {
        #pragma unroll
        for (int t4 = 0; t4 < 4; ++t4)
            #pragma unroll
            for (int r = 0; r < 4; ++r) {
                const int row = i0 + w * 64 + f * 16 + quad * 4 + r;
                num[(so * N_NODES + row) * D + t4 * 16 + li] = f2h(acc[f][t4][r]);
            }
        if (li == 0)
            #pragma unroll
            for (int r = 0; r < 4; ++r)
                den[so * N_NODES + i0 + w * 64 + f * 16 + quad * 4 + r] = c5[f][r];
    }
}

// ---------------------------------------------------------------- gemm finisher body (R8-validated, 128 thr, 32 rows)
__device__ __forceinline__ void gemm_block128(
    const short* __restrict__ Xsrc, const short* __restrict__ WFh,
    const float* __restrict__ av, const float* __restrict__ bv,
    short* __restrict__ WBh, float* __restrict__ fsh, float* __restrict__ fdh,
    unsigned* __restrict__ gmaxp, float* __restrict__ cmh,
    int i0, int t, Smem& sm)
{
    const int w = t >> 6, lane = t & 63;
    const int li = lane & 15, quad = lane >> 4, k0 = quad * 8;
    const int row_a = i0 + w * 16 + li;
    const short* __restrict__ Xr = Xsrc + (size_t)row_a * FDIM;

    f32x4 c0 = {0.f, 0.f, 0.f, 0.f}, c1 = c0, c2 = c0, c3 = c0;
    #pragma unroll 4
    for (int kt = 0; kt < FDIM; kt += 32) {
        f16x8 a = __builtin_bit_cast(f16x8, *(const bf16x8*)&Xr[kt + k0]);
        const short* bb = WFh + (size_t)((kt >> 3) + quad) * (D * 8) + li * 8;
        f16x8 b0 = __builtin_bit_cast(f16x8, *(const bf16x8*)(bb));
        f16x8 b1 = __builtin_bit_cast(f16x8, *(const bf16x8*)(bb + 128));
        f16x8 b2 = __builtin_bit_cast(f16x8, *(const bf16x8*)(bb + 256));
        f16x8 b3 = __builtin_bit_cast(f16x8, *(const bf16x8*)(bb + 384));
        c0 = __builtin_amdgcn_mfma_f32_16x16x32_f16(a, b0, c0, 0, 0, 0);
        c1 = __builtin_amdgcn_mfma_f32_16x16x32_f16(a, b1, c1, 0, 0, 0);
        c2 = __builtin_amdgcn_mfma_f32_16x16x32_f16(a, b2, c2, 0, 0, 0);
        c3 = __builtin_amdgcn_mfma_f32_16x16x32_f16(a, b3, c3, 0, 0, 0);
    }
    float av4[4], bv4[4];
    #pragma unroll
    for (int t4 = 0; t4 < 4; ++t4) {
        av4[t4] = av[t4 * 16 + li];
        bv4[t4] = bv[t4 * 16 + li];
    }
    float tiles[4][4];
    #pragma unroll
    for (int r = 0; r < 4; ++r) { tiles[0][r] = c0[r]; tiles[1][r] = c1[r]; tiles[2][r] = c2[r]; tiles[3][r] = c3[r]; }

    float fdmax = -INFINITY;
    float s4[4] = {0.f, 0.f, 0.f, 0.f};
    #pragma unroll
    for (int r = 0; r < 4; ++r) {
        const int row = i0 + w * 16 + quad * 4 + r;
        float pa = 0.f, pb = 0.f;
        #pragma unroll
        for (int t4 = 0; t4 < 4; ++t4) {
            const float v = tiles[t4][r];
            const int d = t4 * 16 + li;
            WBh[((size_t)(row >> 3)) * (D * 8) + d * 8 + (row & 7)] = f2h(v);
            pa += v * av4[t4];
            pb += v * bv4[t4];
            s4[t4] += v;
        }
        #pragma unroll
        for (int off = 1; off < 16; off <<= 1) {
            pa += __shfl_xor(pa, off);
            pb += __shfl_xor(pb, off);
        }
        if (li == 0) {
            fsh[row] = pa;
            fdh[row] = pb;
        }
        fdmax = fmaxf(fdmax, pb);
    }
    fdmax = fmaxf(fdmax, __shfl_xor(fdmax, 16));
    fdmax = fmaxf(fdmax, __shfl_xor(fdmax, 32));
    if (lane == 0) sm.g.red[w] = fdmax;
    #pragma unroll
    for (int t4 = 0; t4 < 4; ++t4) {
        s4[t4] += __shfl_xor(s4[t4], 16);
        s4[t4] += __shfl_xor(s4[t4], 32);
    }
    if (quad == 0)
        #pragma unroll
        for (int t4 = 0; t4 < 4; ++t4) sm.g.csum[w * 64 + t4 * 16 + li] = s4[t4];
    __syncthreads();
    if (t == 0)
        atomicMax(gmaxp, fenc(fmaxf(sm.g.red[0], sm.g.red[1])));
    if (t < 64)
        atomicAdd(&cmh[t], (sm.g.csum[t] + sm.g.csum[64 + t]) * (1.f / (float)N_NODES));
    __syncthreads();
}

// ---------------------------------------------------------------- layer-1 attention + last-block finishers
// 1024 blocks (32 rb x 8 h x 4 slabs), 128 thr, 4 blocks/CU. After partials:
// last slab of (rb,h) combines -> hcat cols (old k_post1); last head of rb
// then runs layer-2 GEMM for its 128 rows (old k_gemm2). Dependencies flow
// through device-scope {stores -> threadfence -> atomic ticket}; consumer does
// threadfence (acquire) then reads. Kills 2 dispatches (+2 gaps).
__global__ void __launch_bounds__(NTHR, 2) k_accum1m(
    const unsigned int* __restrict__ bits32, const short* __restrict__ WhB,
    const float* __restrict__ fs1, const float* __restrict__ fd1,
    const unsigned* __restrict__ gme1, const float* __restrict__ cm1,
    short* __restrict__ num1, float* __restrict__ den1, short* __restrict__ hcat,
    const short* __restrict__ WoF, const float* __restrict__ ao_src,
    const float* __restrict__ ao_dst, short* __restrict__ WhoB,
    float* __restrict__ fs2, float* __restrict__ fd2,
    unsigned* __restrict__ gme2, float* __restrict__ cm2,
    int* __restrict__ cnt)
{
    __shared__ Smem sm;
    __shared__ int tk1, tk2;
    const int b = blockIdx.x, t = threadIdx.x;
    const int rb = b & 31, h = (b >> 5) & 7, slab = b >> 8;

    accum_slab(bits32, WhB + (size_t)h * (N_NODES / 8) * (D * 8),
               fs1 + (size_t)h * N_NODES, fd1 + (size_t)h * N_NODES,
               fdec(gme1[h]), rb * 128, slab * (N_NODES / S1), N_NODES / S1,
               num1, den1, (size_t)slab * H + h, t, sm);

    // ---- level-1 ticket: last slab of (rb,h) combines -> hcat
    __syncthreads();
    __threadfence();
    if (t == 0) tk1 = atomicAdd(&cnt[rb * 8 + h], 1);
    __syncthreads();
    if (tk1 != S1 - 1) return;
    __threadfence();                               // acquire other slabs' partials

    {
        const int row = rb * 128 + t;
        float ds = 0.f;
        #pragma unroll
        for (int s = 0; s < S1; ++s)
            ds += den1[((size_t)s * H + h) * N_NODES + row];
        sm.p.dsum[t] = ds;
    }
    __syncthreads();
    #pragma unroll 1
    for (int it = 0; it < 64; ++it) {
        const int rr  = it * 2 + (t >> 6);
        const int row = rb * 128 + rr;
        const int col = t & 63;
        float v = 0.f;
        #pragma unroll
        for (int s = 0; s < S1; ++s)
            v += h2f((unsigned short)num1[(((size_t)s * H + h) * N_NODES + row) * D + col]);
        const float ds = sm.p.dsum[rr];
        v = (ds > 0.f) ? v / ds : cm1[h * D + col];
        v = v > 0.f ? v : __expf(v) - 1.f;
        hcat[(size_t)row * (H * D) + h * D + col] = f2h(v);
    }

    // ---- level-2 ticket: last head of rb runs layer-2 GEMM for its 128 rows
    __syncthreads();
    __threadfence();
    if (t == 0) tk2 = atomicAdd(&cnt[256 + rb], 1);
    __syncthreads();
    if (tk2 != H - 1) return;
    __threadfence();                               // acquire all heads' hcat cols
    #pragma unroll 1
    for (int p = 0; p < 4; ++p)
        gemm_block128(hcat, WoF, ao_src, ao_dst, WhoB, fs2, fd2, gme2, cm2,
                      rb * 128 + p * 32, t, sm);
}

// ---------------------------------------------------------------- layer-2 attention + fused log_softmax finisher
// 1024 blocks (32 rb x 32 slabs, ntile=1), 128 thr. Last slab of rb does
// combine + ELU + log_softmax for its 128 rows (old k_lsm).
__global__ void __launch_bounds__(NTHR, 2) k_accum2m(
    const unsigned int* __restrict__ bits32, const short* __restrict__ WhoB,
    const float* __restrict__ fs2, const float* __restrict__ fd2,
    const unsigned* __restrict__ gme2, const float* __restrict__ cm2,
    short* __restrict__ num2, float* __restrict__ den2,
    float* __restrict__ out, int* __restrict__ cnt)
{
    __shared__ Smem sm;
    __shared__ int tk;
    const int b = blockIdx.x, t = threadIdx.x;
    const int rb = b & 31, slab = b >> 5;

    accum_slab(bits32, WhoB, fs2, fd2, fdec(gme2[0]),
               rb * 128, slab * (N_NODES / S2), N_NODES / S2,
               num2, den2, (size_t)slab, t, sm);

    __syncthreads();
    __threadfence();
    if (t == 0) tk = atomicAdd(&cnt[288 + rb], 1);
    __syncthreads();
    if (tk != S2 - 1) return;
    __threadfence();                               // acquire all slabs' partials

    #pragma unroll 1
    for (int it = 0; it < 64; ++it) {
        const int rr  = it * 2 + (t >> 6);
        const int row = rb * 128 + rr;
        const int col = t & 63;
        float v = 0.f, ds = 0.f;
        #pragma unroll
        for (int s = 0; s < S2; ++s)
            v += h2f((unsigned short)num2[((size_t)s * N_NODES + row) * D + col]);
        #pragma unroll
        for (int s = 0; s < S2; ++s)
            ds += den2[(size_t)s * N_NODES + row];
        v = (ds > 0.f) ? v / ds : cm2[col];
        v = v > 0.f ? v : __expf(v) - 1.f;
        float mx = v;
        #pragma unroll
        for (int off = 32; off > 0; off >>= 1) mx = fmaxf(mx, __shfl_xor(mx, off));
        float ex = __expf(v - mx);
        float sum = ex;
        #pragma unroll
        for (int off = 32; off > 0; off >>= 1) sum += __shfl_xor(sum, off);
        out[(size_t)row * D + col] = (v - mx) - __logf(sum);
    }
}

// ----------------------------------------------------------------
extern "C" void kernel_launch(void* const* d_in, const int* in_sizes, int n_in,
                              void* d_out, int out_size, void* d_ws, size_t ws_size,
                              hipStream_t stream) {
    const float* x      = (const float*)d_in[0];
    const int*   adj    = (const int*)d_in[1];
    const float* W      = (const float*)d_in[2];
    const float* a_src  = (const float*)d_in[3];
    const float* a_dst  = (const float*)d_in[4];
    const float* W_o    = (const float*)d_in[5];
    const float* ao_src = (const float*)d_in[6];
    const float* ao_dst = (const float*)d_in[7];
    float* out = (float*)d_out;

    char* wsp = (char*)d_ws;
    size_t off = 0;
    auto alloc = [&](size_t bytes) -> void* {
        void* p = wsp + off;
        off += (bytes + 255) & ~(size_t)255;
        return p;
    };
    unsigned* adj_bits = (unsigned*)alloc((size_t)N_NODES * NWORDS * 8);
    short*    Xbf   = (short*)alloc((size_t)N_NODES * FDIM * 2);
    short*    WF1   = (short*)alloc((size_t)H * 64 * D * 8 * 2);
    short*    WoF   = (short*)alloc((size_t)64 * D * 8 * 2);
    short*    WhB   = (short*)alloc((size_t)H * N_NODES * D * 2);
    float*    fs1   = (float*)alloc((size_t)H * N_NODES * 4);
    float*    fd1   = (float*)alloc((size_t)H * N_NODES * 4);
    unsigned* gme1  = (unsigned*)alloc((size_t)H * 4);
    float*    cm1   = (float*)alloc((size_t)H * D * 4);
    short*    num1  = (short*)alloc((size_t)S1 * H * N_NODES * D * 2);
    float*    den1  = (float*)alloc((size_t)S1 * H * N_NODES * 4);
    short*    hcat  = (short*)alloc((size_t)N_NODES * H * D * 2);
    short*    WhoB  = (short*)alloc((size_t)N_NODES * D * 2);
    float*    fs2   = (float*)alloc((size_t)N_NODES * 4);
    float*    fd2   = (float*)alloc((size_t)N_NODES * 4);
    unsigned* gme2  = (unsigned*)alloc(4);
    float*    cm2   = (float*)alloc((size_t)D * 4);
    short*    num2  = (short*)alloc((size_t)S2 * N_NODES * D * 2);
    float*    den2  = (float*)alloc((size_t)S2 * N_NODES * 4);
    int*      cnt   = (int*)alloc((size_t)320 * 4);

    k_pre   <<<dim3(1 + NB_BITS + NB_X + NB_W + NB_WO), dim3(256), 0, stream>>>(
        adj, x, W, W_o, adj_bits, Xbf, WF1, WoF, cm1, cm2, gme1, gme2, cnt);

    k_gemm  <<<dim3(N_NODES / 64, H), dim3(256), 0, stream>>>(Xbf, WF1, a_src, a_dst,
                                                              WhB, fs1, fd1, gme1, cm1);

    k_accum1m<<<dim3(32 * H * S1), dim3(NTHR), 0, stream>>>(
        adj_bits, WhB, fs1, fd1, gme1, cm1, num1, den1, hcat,
        WoF, ao_src, ao_dst, WhoB, fs2, fd2, gme2, cm2, cnt);

    k_accum2m<<<dim3(32 * S2), dim3(NTHR), 0, stream>>>(
        adj_bits, WhoB, fs2, fd2, gme2, cm2, num2, den2, out, cnt);
}

// Round 10
// 194.240 us; speedup vs baseline: 4.7722x; 2.6027x over previous
//
#include <hip/hip_runtime.h>
#include <hip/hip_bf16.h>
#include <math.h>

#define N_NODES 4096
#define FDIM 512            // K of both GEMMs (F_in = H*D = 512)
#define D 64
#define H 8
#define NWORDS (N_NODES / 64)
#define S1 4                // layer-1 j-slabs  (32 rb x 8 h x 4 = 1024 blocks, proven R3)
#define S2 16               // layer-2 j-slabs  (32 rb x 16 = 512 blocks, proven R3)

typedef __attribute__((ext_vector_type(8))) short bf16x8;      // raw 16B of halfwords
typedef __attribute__((ext_vector_type(4))) float f32x4;
typedef __attribute__((ext_vector_type(8))) _Float16 f16x8;    // MFMA f16 operand
typedef __attribute__((ext_vector_type(2))) _Float16 f16x2;    // packed-pair math
typedef __attribute__((ext_vector_type(4))) unsigned int u32x4;

__device__ inline short f2h(float x) {                         // f32->f16 RNE
    _Float16 h = (_Float16)x;
    return __builtin_bit_cast(short, h);
}
__device__ inline float h2f(unsigned short u) {
    return (float)__builtin_bit_cast(_Float16, u);
}
__device__ inline f16x2 bcH(unsigned int u) { return __builtin_bit_cast(f16x2, u); }

__device__ inline int sext_bit(unsigned int v, int j) {        // all-ones iff bit j set
#if defined(__has_builtin) && __has_builtin(__builtin_amdgcn_sbfe)
    return __builtin_amdgcn_sbfe((int)v, j, 1);
#else
    return ((int)(v << (31 - j))) >> 31;
#endif
}

// monotonic float<->uint encoding so unsigned atomicMax == float max
__device__ inline unsigned fenc(float f) {
    unsigned u = __builtin_bit_cast(unsigned, f);
    return (u & 0x80000000u) ? ~u : (u | 0x80000000u);
}
__device__ inline float fdec(unsigned e) {
    unsigned u = (e & 0x80000000u) ? (e & 0x7FFFFFFFu) : ~e;
    return __builtin_bit_cast(float, u);
}

// async global->LDS 16B copy (DMA). LDS dst must be wave-uniform base + lane*16.
__device__ inline void gl2lds16(const void* g, void* l) {
#if defined(__has_builtin) && __has_builtin(__builtin_amdgcn_global_load_lds)
    __builtin_amdgcn_global_load_lds(
        (const __attribute__((address_space(1))) unsigned int*)g,
        (__attribute__((address_space(3))) unsigned int*)l, 16, 0, 0);
#else
    *(uint4*)l = *(const uint4*)g;
#endif
}

// ---------------------------------------------------------------- fused preprocessing (proven R0-R3)
// band 0: zero cm/gmax; bands: adj->bits (8/thread, int4 loads) | X->f16 | W | W_o
#define NB_BITS (N_NODES * N_NODES / 2048)
#define NB_X    (N_NODES * FDIM / 1024)
#define NB_W    (H * FDIM * D / 256)
#define NB_WO   (FDIM * D / 256)
__global__ void k_pre(const int* __restrict__ adj, const float* __restrict__ x,
                      const float* __restrict__ W, const float* __restrict__ Wo,
                      unsigned int* __restrict__ bits32, short* __restrict__ Xbf,
                      short* __restrict__ WF, short* __restrict__ WoF,
                      float* __restrict__ cm1, float* __restrict__ cm2,
                      unsigned* __restrict__ gmaxe1, unsigned* __restrict__ gmaxe2) {
    const int b = blockIdx.x, t = threadIdx.x;
    if (b == 0) {
        for (int i = t; i < H * D; i += 256) cm1[i] = 0.f;
        if (t < D) cm2[t] = 0.f;
        if (t < H) gmaxe1[t] = 0u;
        if (t == 0) gmaxe2[0] = 0u;
        return;
    }
    if (b < 1 + NB_BITS) {
        const int tid  = (b - 1) * 256 + t;     // one byte (8 adj) per thread
        const size_t e0 = (size_t)tid * 8;
        int4 a0 = *(const int4*)&adj[e0];
        int4 a1 = *(const int4*)&adj[e0 + 4];
        unsigned by = (unsigned)(a0.x != 0)       | ((unsigned)(a0.y != 0) << 1)
                    | ((unsigned)(a0.z != 0) << 2) | ((unsigned)(a0.w != 0) << 3)
                    | ((unsigned)(a1.x != 0) << 4) | ((unsigned)(a1.y != 0) << 5)
                    | ((unsigned)(a1.z != 0) << 6) | ((unsigned)(a1.w != 0) << 7);
        unsigned v = by | (__shfl_xor((int)by, 1) << 8);
        v = v | ((unsigned)__shfl_xor((int)v, 2) << 16);
        if ((t & 3) == 0) bits32[tid >> 2] = v;
        return;
    }
    if (b < 1 + NB_BITS + NB_X) {
        const size_t i4 = ((size_t)(b - 1 - NB_BITS) * 256 + t) * 4;
        float4 v = *(const float4*)&x[i4];
        ushort4 o;
        o.x = (unsigned short)f2h(v.x); o.y = (unsigned short)f2h(v.y);
        o.z = (unsigned short)f2h(v.z); o.w = (unsigned short)f2h(v.w);
        *(ushort4*)&Xbf[i4] = o;
        return;
    }
    if (b < 1 + NB_BITS + NB_X + NB_W) {
        const size_t idx = (size_t)(b - 1 - NB_BITS - NB_X) * 256 + t;   // (h*512+k)*64+d
        const int d = idx & 63;
        const int k = (int)(idx >> 6) & 511;
        const int h = (int)(idx >> 15);
        WF[(((size_t)h * 64 + (k >> 3)) * 64 + d) * 8 + (k & 7)] = f2h(W[idx]);
        return;
    }
    {
        const size_t idx = (size_t)(b - 1 - NB_BITS - NB_X - NB_W) * 256 + t;  // k*64+d
        const int d = idx & 63;
        const int k = (int)(idx >> 6);
        WoF[(((size_t)(k >> 3)) * 64 + d) * 8 + (k & 7)] = f2h(Wo[idx]);
    }
}

// ---------------------------------------------------------------- MFMA GEMM layer-1 (proven R0-R3, 256 thr)
__global__ void __launch_bounds__(256) k_gemm(
    const short* __restrict__ Xbf, const short* __restrict__ WF,
    const float* __restrict__ av, const float* __restrict__ bv,
    short* __restrict__ WBout, float* __restrict__ fs, float* __restrict__ fd,
    unsigned* __restrict__ gmaxe, float* __restrict__ cm) {
    const int h  = blockIdx.y;
    const int i0 = blockIdx.x * 64;
    const int t = threadIdx.x, w = t >> 6, lane = t & 63;
    const int li = lane & 15, quad = lane >> 4, k0 = quad * 8;
    const int row_a = i0 + w * 16 + li;
    const short* __restrict__ Xr  = Xbf + (size_t)row_a * FDIM;
    const short* __restrict__ WFh = WF + (size_t)h * 64 * D * 8;

    f32x4 c0 = {0.f, 0.f, 0.f, 0.f}, c1 = c0, c2 = c0, c3 = c0;
    #pragma unroll 4
    for (int kt = 0; kt < FDIM; kt += 32) {
        f16x8 a = __builtin_bit_cast(f16x8, *(const bf16x8*)&Xr[kt + k0]);
        const short* bb = WFh + (size_t)((kt >> 3) + quad) * (D * 8) + li * 8;
        f16x8 b0 = __builtin_bit_cast(f16x8, *(const bf16x8*)(bb));
        f16x8 b1 = __builtin_bit_cast(f16x8, *(const bf16x8*)(bb + 128));
        f16x8 b2 = __builtin_bit_cast(f16x8, *(const bf16x8*)(bb + 256));
        f16x8 b3 = __builtin_bit_cast(f16x8, *(const bf16x8*)(bb + 384));
        c0 = __builtin_amdgcn_mfma_f32_16x16x32_f16(a, b0, c0, 0, 0, 0);
        c1 = __builtin_amdgcn_mfma_f32_16x16x32_f16(a, b1, c1, 0, 0, 0);
        c2 = __builtin_amdgcn_mfma_f32_16x16x32_f16(a, b2, c2, 0, 0, 0);
        c3 = __builtin_amdgcn_mfma_f32_16x16x32_f16(a, b3, c3, 0, 0, 0);
    }
    float av4[4], bv4[4];
    #pragma unroll
    for (int t4 = 0; t4 < 4; ++t4) {
        av4[t4] = av[h * D + t4 * 16 + li];
        bv4[t4] = bv[h * D + t4 * 16 + li];
    }
    float tiles[4][4];
    #pragma unroll
    for (int r = 0; r < 4; ++r) { tiles[0][r] = c0[r]; tiles[1][r] = c1[r]; tiles[2][r] = c2[r]; tiles[3][r] = c3[r]; }

    __shared__ float csum[4][64];
    __shared__ float red[4];
    float fdmax = -INFINITY;
    float s4[4] = {0.f, 0.f, 0.f, 0.f};

    #pragma unroll
    for (int r = 0; r < 4; ++r) {
        const int row = i0 + w * 16 + quad * 4 + r;
        float pa = 0.f, pb = 0.f;
        #pragma unroll
        for (int t4 = 0; t4 < 4; ++t4) {
            const float v = tiles[t4][r];
            const int d = t4 * 16 + li;
            WBout[((size_t)h * (N_NODES / 8) + (row >> 3)) * (D * 8) + d * 8 + (row & 7)] = f2h(v);
            pa += v * av4[t4];
            pb += v * bv4[t4];
            s4[t4] += v;
        }
        #pragma unroll
        for (int off = 1; off < 16; off <<= 1) {
            pa += __shfl_xor(pa, off);
            pb += __shfl_xor(pb, off);
        }
        if (li == 0) {
            fs[(size_t)h * N_NODES + row] = pa;
            fd[(size_t)h * N_NODES + row] = pb;
        }
        fdmax = fmaxf(fdmax, pb);
    }
    fdmax = fmaxf(fdmax, __shfl_xor(fdmax, 16));
    fdmax = fmaxf(fdmax, __shfl_xor(fdmax, 32));
    if (lane == 0) red[w] = fdmax;
    #pragma unroll
    for (int t4 = 0; t4 < 4; ++t4) {
        s4[t4] += __shfl_xor(s4[t4], 16);
        s4[t4] += __shfl_xor(s4[t4], 32);
    }
    if (quad == 0)
        #pragma unroll
        for (int t4 = 0; t4 < 4; ++t4) csum[w][t4 * 16 + li] = s4[t4];
    __syncthreads();
    if (t == 0)
        atomicMax(gmaxe + h, fenc(fmaxf(fmaxf(red[0], red[1]), fmaxf(red[2], red[3]))));
    if (t < 64)
        atomicAdd(&cm[h * D + t],
                  (csum[0][t] + csum[1][t] + csum[2][t] + csum[3][t]) * (1.f / (float)N_NODES));
}

// ---------------------------------------------------------------- MFMA attention aggregation (proven R3 shape)
// 128-thr blocks, 2 waves x 64 rows (F=4), j-slab split; DMA-staged B-tiles,
// 2-phase syncthreads schedule. LDS 36,864 B -> 4 blocks/CU.
__global__ void __launch_bounds__(128, 2) k_accum(
    const unsigned int* __restrict__ bits32,
    const short* __restrict__ WB,
    const float* __restrict__ fsb, const float* __restrict__ fdb,
    const unsigned* __restrict__ gmaxe,
    short* __restrict__ num, float* __restrict__ den, int kslab) {

    __shared__ __align__(16) short Bt[2][16 * 64 * 8];   // 2 x 16 KB
    __shared__ __align__(16) short Esh[1024];            // f16: exp(fd - gm), whole slab
    __shared__ __align__(16) short Gsh[1024];            // f16: exp(0.2*(fd - gm))

    const int h = blockIdx.y, i0 = blockIdx.x * 128, slab = blockIdx.z;
    const int t = threadIdx.x, w = t >> 6, lane = t & 63;
    const int li = lane & 15, quad = lane >> 4, k0 = quad * 8;
    const size_t ho = (size_t)h * N_NODES;
    const float  gm = fdec(gmaxe[h]);
    const float* __restrict__ fd = fdb + ho;
    const short* __restrict__ Bh = WB + (size_t)h * (N_NODES / 8) * D * 8;

    const int k_beg = slab * kslab;
    const int ntile = kslab / 128;

    auto stage = [&](int buf, int jtile) {
        const short* src = Bh + (size_t)(jtile >> 3) * (D * 8);
        #pragma unroll
        for (int p = 0; p < 8; ++p)
            gl2lds16(src + (size_t)(p * 128 + t) * 8, &Bt[buf][(p * 128 + t) * 8]);
    };

    int bito[4];
    #pragma unroll
    for (int f = 0; f < 4; ++f)
        bito[f] = (i0 + w * 64 + f * 16 + li) * (NWORDS * 2);
    stage(0, k_beg);
    for (int jj = t * 2; jj < kslab; jj += 256) {        // whole-slab EG table
        float2 f2 = *(const float2*)&fd[k_beg + jj];
        f16x2 ep = {(_Float16)__expf(f2.x - gm), (_Float16)__expf(f2.y - gm)};
        f16x2 gp = {(_Float16)__expf(0.2f * (f2.x - gm)),
                    (_Float16)__expf(0.2f * (f2.y - gm))};
        *(f16x2*)&Esh[jj] = ep;
        *(f16x2*)&Gsh[jj] = gp;
    }
    f16x2 Rp[4];
    #pragma unroll
    for (int f = 0; f < 4; ++f) {
        const float rv = __expf(-0.8f * (fsb[ho + i0 + w * 64 + f * 16 + li] + gm));
        const _Float16 rh = (_Float16)rv;
        Rp[f] = (f16x2){rh, rh};
    }

    f32x4 acc[4][4], c5[4];
    #pragma unroll
    for (int f = 0; f < 4; ++f) {
        #pragma unroll
        for (int q = 0; q < 4; ++q) acc[f][q] = (f32x4){0.f, 0.f, 0.f, 0.f};
        c5[f] = (f32x4){0.f, 0.f, 0.f, 0.f};
    }
    bf16x8 ones_;
    #pragma unroll
    for (int j = 0; j < 8; ++j) ones_[j] = (short)0x3C00;    // f16 1.0
    const f16x8 ones = __builtin_bit_cast(f16x8, ones_);

    __syncthreads();   // stage(0) + EG landed

    for (int tile = 0; tile < ntile; ++tile) {
        const int jt = k_beg + tile * 128;
        if (tile + 1 < ntile) stage((tile + 1) & 1, jt + 128);

        uint4 bw[4];
        #pragma unroll
        for (int f = 0; f < 4; ++f)
            bw[f] = *(const uint4*)&bits32[(size_t)bito[f] + (jt >> 5)];

        const short* Bl = Bt[tile & 1];
        const short* Ee = Esh + tile * 128;
        const short* Gg = Gsh + tile * 128;
        #pragma unroll
        for (int s = 0; s < 4; ++s) {
            const uint4 Eu = *(const uint4*)&Ee[s * 32 + k0];   // 8 f16 (broadcast per quad)
            const uint4 Gu = *(const uint4*)&Gg[s * 32 + k0];
            f16x2 Ep[4] = {bcH(Eu.x), bcH(Eu.y), bcH(Eu.z), bcH(Eu.w)};
            f16x2 Gp[4] = {bcH(Gu.x), bcH(Gu.y), bcH(Gu.z), bcH(Gu.w)};
            const short* bb = Bl + (size_t)((s * 4 + quad) * 64 + li) * 8;
            f16x8 b0 = __builtin_bit_cast(f16x8, *(const bf16x8*)(bb));
            f16x8 b1 = __builtin_bit_cast(f16x8, *(const bf16x8*)(bb + 128));
            f16x8 b2 = __builtin_bit_cast(f16x8, *(const bf16x8*)(bb + 256));
            f16x8 b3 = __builtin_bit_cast(f16x8, *(const bf16x8*)(bb + 384));
            #pragma unroll
            for (int f = 0; f < 4; ++f) {
                const unsigned int wsel = (s == 0) ? bw[f].x : (s == 1) ? bw[f].y
                                        : (s == 2) ? bw[f].z : bw[f].w;
                const unsigned int byt = (wsel >> k0) & 0xFFu;
                u32x4 au;
                #pragma unroll
                for (int d2 = 0; d2 < 4; ++d2) {
                    const unsigned mw = (unsigned)__builtin_amdgcn_perm(
                        (unsigned)sext_bit(byt, 2 * d2 + 1),
                        (unsigned)sext_bit(byt, 2 * d2), 0x05040100u);
                    const f16x2 tv = Gp[d2] * Rp[f];                       // v_pk_mul_f16
                    const f16x2 pv = __builtin_elementwise_max(Ep[d2], tv); // v_pk_max_f16
                    au[d2] = __builtin_bit_cast(unsigned, pv) & mw;
                }
                const f16x8 a = __builtin_bit_cast(f16x8, au);
                __builtin_amdgcn_s_setprio(1);
                acc[f][0] = __builtin_amdgcn_mfma_f32_16x16x32_f16(a, b0, acc[f][0], 0, 0, 0);
                acc[f][1] = __builtin_amdgcn_mfma_f32_16x16x32_f16(a, b1, acc[f][1], 0, 0, 0);
                acc[f][2] = __builtin_amdgcn_mfma_f32_16x16x32_f16(a, b2, acc[f][2], 0, 0, 0);
                acc[f][3] = __builtin_amdgcn_mfma_f32_16x16x32_f16(a, b3, acc[f][3], 0, 0, 0);
                c5[f]     = __builtin_amdgcn_mfma_f32_16x16x32_f16(a, ones, c5[f], 0, 0, 0);
                __builtin_amdgcn_s_setprio(0);
            }
        }
        __syncthreads();
    }

    const size_t so = (size_t)(slab * gridDim.y + h);
    #pragma unroll
    for (int f = 0; f < 4; ++f) {
        #pragma unroll
        for (int t4 = 0; t4 < 4; ++t4)
            #pragma unroll
            for (int r = 0; r < 4; ++r) {
                const int row = i0 + w * 64 + f * 16 + quad * 4 + r;
                num[(so * N_NODES + row) * D + t4 * 16 + li] = f2h(acc[f][t4][r]);
            }
        if (li == 0)
            #pragma unroll
            for (int r = 0; r < 4; ++r)
                den[so * N_NODES + i0 + w * 64 + f * 16 + quad * 4 + r] = c5[f][r];
    }
}

// ---------------------------------------------------------------- layer-1 combine FUSED INTO layer-2 GEMM
// Replaces {k_post1, k_gemm2}: each thread combines num1/den1 (its rows x its
// A-fragment columns, ROW-LOCAL -> no cross-block dependency), applies the
// colmean fallback + ELU, and packs the layer-2 A-fragments directly in
// REGISTERS (16x f16x8 = 64 VGPR). hcat is never materialized. Then the
// standard MFMA GEMM vs WoF with fused fs2/fd2/gmax2/cm2 stats.
// Grid: 128 blocks x 128 thr (2 waves x 16 rows = 32 rows/block).
__global__ void __launch_bounds__(128) k_gemm2f(
    const short* __restrict__ num1, const float* __restrict__ den1,
    const float* __restrict__ cm1, const short* __restrict__ WoF,
    const float* __restrict__ av, const float* __restrict__ bv,
    short* __restrict__ WBout, float* __restrict__ fs, float* __restrict__ fd,
    unsigned* __restrict__ gmaxe, float* __restrict__ cm) {

    const int i0 = blockIdx.x * 32;
    const int t = threadIdx.x, w = t >> 6, lane = t & 63;
    const int li = lane & 15, quad = lane >> 4, k0 = quad * 8;
    const int row = i0 + w * 16 + li;          // A-row this lane owns

    // per-head denominator sums for this row
    float ds8[8];
    #pragma unroll
    for (int h = 0; h < 8; ++h) {
        float ds = 0.f;
        #pragma unroll
        for (int s = 0; s < S1; ++s)
            ds += den1[((size_t)s * H + h) * N_NODES + row];
        ds8[h] = ds;
    }

    // build the 16 A-fragments (chunk c covers cols c*32 + k0 .. +8)
    f16x8 afr[16];
    #pragma unroll
    for (int c = 0; c < 16; ++c) {
        const int col512 = c * 32 + k0;
        const int h   = col512 >> 6;
        const int col = col512 & 63;
        float v8[8] = {0.f, 0.f, 0.f, 0.f, 0.f, 0.f, 0.f, 0.f};
        #pragma unroll
        for (int s = 0; s < S1; ++s) {
            bf16x8 nv = *(const bf16x8*)&num1[(((size_t)s * H + h) * N_NODES + row) * D + col];
            #pragma unroll
            for (int j = 0; j < 8; ++j) v8[j] += h2f((unsigned short)nv[j]);
        }
        const bool  uni  = !(ds8[h] > 0.f);
        const float linv = uni ? 0.f : 1.f / ds8[h];
        bf16x8 o;
        #pragma unroll
        for (int j = 0; j < 8; ++j) {
            float v = v8[j] * linv;
            if (uni) v = cm1[h * D + col + j];
            v = v > 0.f ? v : __expf(v) - 1.f;
            o[j] = f2h(v);
        }
        afr[c] = __builtin_bit_cast(f16x8, o);
    }

    // layer-2 GEMM: A from registers, B = WoF
    f32x4 c0 = {0.f, 0.f, 0.f, 0.f}, c1 = c0, c2 = c0, c3 = c0;
    #pragma unroll
    for (int c = 0; c < 16; ++c) {
        const int kt = c * 32;
        const f16x8 a = afr[c];
        const short* bb = WoF + (size_t)((kt >> 3) + quad) * (D * 8) + li * 8;
        f16x8 b0 = __builtin_bit_cast(f16x8, *(const bf16x8*)(bb));
        f16x8 b1 = __builtin_bit_cast(f16x8, *(const bf16x8*)(bb + 128));
        f16x8 b2 = __builtin_bit_cast(f16x8, *(const bf16x8*)(bb + 256));
        f16x8 b3 = __builtin_bit_cast(f16x8, *(const bf16x8*)(bb + 384));
        c0 = __builtin_amdgcn_mfma_f32_16x16x32_f16(a, b0, c0, 0, 0, 0);
        c1 = __builtin_amdgcn_mfma_f32_16x16x32_f16(a, b1, c1, 0, 0, 0);
        c2 = __builtin_amdgcn_mfma_f32_16x16x32_f16(a, b2, c2, 0, 0, 0);
        c3 = __builtin_amdgcn_mfma_f32_16x16x32_f16(a, b3, c3, 0, 0, 0);
    }

    float av4[4], bv4[4];
    #pragma unroll
    for (int t4 = 0; t4 < 4; ++t4) {
        av4[t4] = av[t4 * 16 + li];
        bv4[t4] = bv[t4 * 16 + li];
    }
    float tiles[4][4];
    #pragma unroll
    for (int r = 0; r < 4; ++r) { tiles[0][r] = c0[r]; tiles[1][r] = c1[r]; tiles[2][r] = c2[r]; tiles[3][r] = c3[r]; }

    __shared__ float csum[2][64];
    __shared__ float red[2];
    float fdmax = -INFINITY;
    float s4[4] = {0.f, 0.f, 0.f, 0.f};

    #pragma unroll
    for (int r = 0; r < 4; ++r) {
        const int orow = i0 + w * 16 + quad * 4 + r;
        float pa = 0.f, pb = 0.f;
        #pragma unroll
        for (int t4 = 0; t4 < 4; ++t4) {
            const float v = tiles[t4][r];
            const int d = t4 * 16 + li;
            WBout[((size_t)(orow >> 3)) * (D * 8) + d * 8 + (orow & 7)] = f2h(v);
            pa += v * av4[t4];
            pb += v * bv4[t4];
            s4[t4] += v;
        }
        #pragma unroll
        for (int off = 1; off < 16; off <<= 1) {
            pa += __shfl_xor(pa, off);
            pb += __shfl_xor(pb, off);
        }
        if (li == 0) {
            fs[orow] = pa;
            fd[orow] = pb;
        }
        fdmax = fmaxf(fdmax, pb);
    }
    fdmax = fmaxf(fdmax, __shfl_xor(fdmax, 16));
    fdmax = fmaxf(fdmax, __shfl_xor(fdmax, 32));
    if (lane == 0) red[w] = fdmax;
    #pragma unroll
    for (int t4 = 0; t4 < 4; ++t4) {
        s4[t4] += __shfl_xor(s4[t4], 16);
        s4[t4] += __shfl_xor(s4[t4], 32);
    }
    if (quad == 0)
        #pragma unroll
        for (int t4 = 0; t4 < 4; ++t4) csum[w][t4 * 16 + li] = s4[t4];
    __syncthreads();
    if (t == 0)
        atomicMax(gmaxe, fenc(fmaxf(red[0], red[1])));
    if (t < 64)
        atomicAdd(&cm[t], (csum[0][t] + csum[1][t]) * (1.f / (float)N_NODES));
}

// ---------------------------------------------------------------- layer-2 combine (JS=S2) + ELU + log_softmax
__global__ void k_lsm(const short* __restrict__ num, const float* __restrict__ den,
                      const float* __restrict__ cm, float* __restrict__ out) {
    const int n    = blockIdx.x * 4 + (threadIdx.x >> 6);
    const int lane = threadIdx.x & 63;
    float v = 0.f, ds = 0.f;
    #pragma unroll
    for (int s = 0; s < S2; ++s)
        v += h2f((unsigned short)num[((size_t)s * N_NODES + n) * D + lane]);
    #pragma unroll
    for (int s = 0; s < S2; ++s) ds += den[(size_t)s * N_NODES + n];
    v = (ds > 0.f) ? v / ds : cm[lane];
    v = v > 0.f ? v : __expf(v) - 1.f;
    float mx = v;
    #pragma unroll
    for (int off = 32; off > 0; off >>= 1) mx = fmaxf(mx, __shfl_xor(mx, off));
    float ex = __expf(v - mx);
    float sum = ex;
    #pragma unroll
    for (int off = 32; off > 0; off >>= 1) sum += __shfl_xor(sum, off);
    out[(size_t)n * D + lane] = (v - mx) - __logf(sum);
}

// ----------------------------------------------------------------
extern "C" void kernel_launch(void* const* d_in, const int* in_sizes, int n_in,
                              void* d_out, int out_size, void* d_ws, size_t ws_size,
                              hipStream_t stream) {
    const float* x      = (const float*)d_in[0];
    const int*   adj    = (const int*)d_in[1];
    const float* W      = (const float*)d_in[2];
    const float* a_src  = (const float*)d_in[3];
    const float* a_dst  = (const float*)d_in[4];
    const float* W_o    = (const float*)d_in[5];
    const float* ao_src = (const float*)d_in[6];
    const float* ao_dst = (const float*)d_in[7];
    float* out = (float*)d_out;

    char* wsp = (char*)d_ws;
    size_t off = 0;
    auto alloc = [&](size_t bytes) -> void* {
        void* p = wsp + off;
        off += (bytes + 255) & ~(size_t)255;
        return p;
    };
    unsigned* adj_bits = (unsigned*)alloc((size_t)N_NODES * NWORDS * 8);
    short*    Xbf   = (short*)alloc((size_t)N_NODES * FDIM * 2);
    short*    WF1   = (short*)alloc((size_t)H * 64 * D * 8 * 2);
    short*    WoF   = (short*)alloc((size_t)64 * D * 8 * 2);
    short*    WhB   = (short*)alloc((size_t)H * N_NODES * D * 2);
    float*    fs1   = (float*)alloc((size_t)H * N_NODES * 4);
    float*    fd1   = (float*)alloc((size_t)H * N_NODES * 4);
    unsigned* gme1  = (unsigned*)alloc((size_t)H * 4);
    float*    cm1   = (float*)alloc((size_t)H * D * 4);
    short*    num1  = (short*)alloc((size_t)S1 * H * N_NODES * D * 2);
    float*    den1  = (float*)alloc((size_t)S1 * H * N_NODES * 4);
    short*    WhoB  = (short*)alloc((size_t)N_NODES * D * 2);
    float*    fs2   = (float*)alloc((size_t)N_NODES * 4);
    float*    fd2   = (float*)alloc((size_t)N_NODES * 4);
    unsigned* gme2  = (unsigned*)alloc(4);
    float*    cm2   = (float*)alloc((size_t)D * 4);
    short*    num2  = (short*)alloc((size_t)S2 * N_NODES * D * 2);
    float*    den2  = (float*)alloc((size_t)S2 * N_NODES * 4);

    k_pre  <<<dim3(1 + NB_BITS + NB_X + NB_W + NB_WO), dim3(256), 0, stream>>>(
        adj, x, W, W_o, adj_bits, Xbf, WF1, WoF, cm1, cm2, gme1, gme2);

    // layer 1 (8 heads)
    k_gemm <<<dim3(N_NODES / 64, H), dim3(256), 0, stream>>>(Xbf, WF1, a_src, a_dst,
                                                             WhB, fs1, fd1, gme1, cm1);
    k_accum<<<dim3(N_NODES / 128, H, S1), dim3(128), 0, stream>>>(adj_bits, WhB, fs1, fd1, gme1,
                                                                  num1, den1, N_NODES / S1);

    // layer-1 combine fused into layer-2 GEMM (hcat never materialized)
    k_gemm2f<<<dim3(N_NODES / 32), dim3(128), 0, stream>>>(num1, den1, cm1, WoF,
                                                           ao_src, ao_dst,
                                                           WhoB, fs2, fd2, gme2, cm2);

    // layer 2 (single output head)
    k_accum<<<dim3(N_NODES / 128, 1, S2), dim3(128), 0, stream>>>(adj_bits, WhoB, fs2, fd2, gme2,
                                                                  num2, den2, N_NODES / S2);
    k_lsm  <<<dim3(N_NODES / 4), dim3(256), 0, stream>>>(num2, den2, cm2, out);
}

// Round 11
// 188.029 us; speedup vs baseline: 4.9298x; 1.0330x over previous
//
#include <hip/hip_runtime.h>
#include <hip/hip_bf16.h>
#include <math.h>

#define N_NODES 4096
#define FDIM 512            // K of both GEMMs (F_in = H*D = 512)
#define D 64
#define H 8
#define NWORDS (N_NODES / 64)
#define S1 4                // layer-1 j-slabs  (32 rb x 8 h x 4 = 1024 blocks, proven R3)
#define S2 16               // layer-2 j-slabs  (32 rb x 16 = 512 blocks, proven R3)

typedef __attribute__((ext_vector_type(8))) short bf16x8;      // raw 16B of halfwords
typedef __attribute__((ext_vector_type(4))) float f32x4;
typedef __attribute__((ext_vector_type(8))) _Float16 f16x8;    // MFMA f16 operand
typedef __attribute__((ext_vector_type(2))) _Float16 f16x2;    // packed-pair math
typedef __attribute__((ext_vector_type(4))) unsigned int u32x4;

__device__ inline short f2h(float x) {                         // f32->f16 RNE
    _Float16 h = (_Float16)x;
    return __builtin_bit_cast(short, h);
}
__device__ inline float h2f(unsigned short u) {
    return (float)__builtin_bit_cast(_Float16, u);
}
__device__ inline f16x2 bcH(unsigned int u) { return __builtin_bit_cast(f16x2, u); }

__device__ inline int sext_bit(unsigned int v, int j) {        // all-ones iff bit j set
#if defined(__has_builtin) && __has_builtin(__builtin_amdgcn_sbfe)
    return __builtin_amdgcn_sbfe((int)v, j, 1);
#else
    return ((int)(v << (31 - j))) >> 31;
#endif
}

// monotonic float<->uint encoding so unsigned atomicMax == float max
__device__ inline unsigned fenc(float f) {
    unsigned u = __builtin_bit_cast(unsigned, f);
    return (u & 0x80000000u) ? ~u : (u | 0x80000000u);
}
__device__ inline float fdec(unsigned e) {
    unsigned u = (e & 0x80000000u) ? (e & 0x7FFFFFFFu) : ~e;
    return __builtin_bit_cast(float, u);
}

// async global->LDS 16B copy (DMA). LDS dst must be wave-uniform base + lane*16.
__device__ inline void gl2lds16(const void* g, void* l) {
#if defined(__has_builtin) && __has_builtin(__builtin_amdgcn_global_load_lds)
    __builtin_amdgcn_global_load_lds(
        (const __attribute__((address_space(1))) unsigned int*)g,
        (__attribute__((address_space(3))) unsigned int*)l, 16, 0, 0);
#else
    *(uint4*)l = *(const uint4*)g;
#endif
}

// ---------------------------------------------------------------- fused preprocessing (proven R0-R3)
// band 0: zero cm/gmax; bands: adj->bits (8/thread, int4 loads) | X->f16 | W | W_o
#define NB_BITS (N_NODES * N_NODES / 2048)
#define NB_X    (N_NODES * FDIM / 1024)
#define NB_W    (H * FDIM * D / 256)
#define NB_WO   (FDIM * D / 256)
__global__ void k_pre(const int* __restrict__ adj, const float* __restrict__ x,
                      const float* __restrict__ W, const float* __restrict__ Wo,
                      unsigned int* __restrict__ bits32, short* __restrict__ Xbf,
                      short* __restrict__ WF, short* __restrict__ WoF,
                      float* __restrict__ cm1, float* __restrict__ cm2,
                      unsigned* __restrict__ gmaxe1, unsigned* __restrict__ gmaxe2) {
    const int b = blockIdx.x, t = threadIdx.x;
    if (b == 0) {
        for (int i = t; i < H * D; i += 256) cm1[i] = 0.f;
        if (t < D) cm2[t] = 0.f;
        if (t < H) gmaxe1[t] = 0u;
        if (t == 0) gmaxe2[0] = 0u;
        return;
    }
    if (b < 1 + NB_BITS) {
        const int tid  = (b - 1) * 256 + t;     // one byte (8 adj) per thread
        const size_t e0 = (size_t)tid * 8;
        int4 a0 = *(const int4*)&adj[e0];
        int4 a1 = *(const int4*)&adj[e0 + 4];
        unsigned by = (unsigned)(a0.x != 0)       | ((unsigned)(a0.y != 0) << 1)
                    | ((unsigned)(a0.z != 0) << 2) | ((unsigned)(a0.w != 0) << 3)
                    | ((unsigned)(a1.x != 0) << 4) | ((unsigned)(a1.y != 0) << 5)
                    | ((unsigned)(a1.z != 0) << 6) | ((unsigned)(a1.w != 0) << 7);
        unsigned v = by | (__shfl_xor((int)by, 1) << 8);
        v = v | ((unsigned)__shfl_xor((int)v, 2) << 16);
        if ((t & 3) == 0) bits32[tid >> 2] = v;
        return;
    }
    if (b < 1 + NB_BITS + NB_X) {
        const size_t i4 = ((size_t)(b - 1 - NB_BITS) * 256 + t) * 4;
        float4 v = *(const float4*)&x[i4];
        ushort4 o;
        o.x = (unsigned short)f2h(v.x); o.y = (unsigned short)f2h(v.y);
        o.z = (unsigned short)f2h(v.z); o.w = (unsigned short)f2h(v.w);
        *(ushort4*)&Xbf[i4] = o;
        return;
    }
    if (b < 1 + NB_BITS + NB_X + NB_W) {
        const size_t idx = (size_t)(b - 1 - NB_BITS - NB_X) * 256 + t;   // (h*512+k)*64+d
        const int d = idx & 63;
        const int k = (int)(idx >> 6) & 511;
        const int h = (int)(idx >> 15);
        WF[(((size_t)h * 64 + (k >> 3)) * 64 + d) * 8 + (k & 7)] = f2h(W[idx]);
        return;
    }
    {
        const size_t idx = (size_t)(b - 1 - NB_BITS - NB_X - NB_W) * 256 + t;  // k*64+d
        const int d = idx & 63;
        const int k = (int)(idx >> 6);
        WoF[(((size_t)(k >> 3)) * 64 + d) * 8 + (k & 7)] = f2h(Wo[idx]);
    }
}

// ---------------------------------------------------------------- MFMA GEMM layer-1 (proven R0-R3, 256 thr)
__global__ void __launch_bounds__(256) k_gemm(
    const short* __restrict__ Xbf, const short* __restrict__ WF,
    const float* __restrict__ av, const float* __restrict__ bv,
    short* __restrict__ WBout, float* __restrict__ fs, float* __restrict__ fd,
    unsigned* __restrict__ gmaxe, float* __restrict__ cm) {
    const int h  = blockIdx.y;
    const int i0 = blockIdx.x * 64;
    const int t = threadIdx.x, w = t >> 6, lane = t & 63;
    const int li = lane & 15, quad = lane >> 4, k0 = quad * 8;
    const int row_a = i0 + w * 16 + li;
    const short* __restrict__ Xr  = Xbf + (size_t)row_a * FDIM;
    const short* __restrict__ WFh = WF + (size_t)h * 64 * D * 8;

    f32x4 c0 = {0.f, 0.f, 0.f, 0.f}, c1 = c0, c2 = c0, c3 = c0;
    #pragma unroll 4
    for (int kt = 0; kt < FDIM; kt += 32) {
        f16x8 a = __builtin_bit_cast(f16x8, *(const bf16x8*)&Xr[kt + k0]);
        const short* bb = WFh + (size_t)((kt >> 3) + quad) * (D * 8) + li * 8;
        f16x8 b0 = __builtin_bit_cast(f16x8, *(const bf16x8*)(bb));
        f16x8 b1 = __builtin_bit_cast(f16x8, *(const bf16x8*)(bb + 128));
        f16x8 b2 = __builtin_bit_cast(f16x8, *(const bf16x8*)(bb + 256));
        f16x8 b3 = __builtin_bit_cast(f16x8, *(const bf16x8*)(bb + 384));
        c0 = __builtin_amdgcn_mfma_f32_16x16x32_f16(a, b0, c0, 0, 0, 0);
        c1 = __builtin_amdgcn_mfma_f32_16x16x32_f16(a, b1, c1, 0, 0, 0);
        c2 = __builtin_amdgcn_mfma_f32_16x16x32_f16(a, b2, c2, 0, 0, 0);
        c3 = __builtin_amdgcn_mfma_f32_16x16x32_f16(a, b3, c3, 0, 0, 0);
    }
    float av4[4], bv4[4];
    #pragma unroll
    for (int t4 = 0; t4 < 4; ++t4) {
        av4[t4] = av[h * D + t4 * 16 + li];
        bv4[t4] = bv[h * D + t4 * 16 + li];
    }
    float tiles[4][4];
    #pragma unroll
    for (int r = 0; r < 4; ++r) { tiles[0][r] = c0[r]; tiles[1][r] = c1[r]; tiles[2][r] = c2[r]; tiles[3][r] = c3[r]; }

    __shared__ float csum[4][64];
    __shared__ float red[4];
    float fdmax = -INFINITY;
    float s4[4] = {0.f, 0.f, 0.f, 0.f};

    #pragma unroll
    for (int r = 0; r < 4; ++r) {
        const int row = i0 + w * 16 + quad * 4 + r;
        float pa = 0.f, pb = 0.f;
        #pragma unroll
        for (int t4 = 0; t4 < 4; ++t4) {
            const float v = tiles[t4][r];
            const int d = t4 * 16 + li;
            WBout[((size_t)h * (N_NODES / 8) + (row >> 3)) * (D * 8) + d * 8 + (row & 7)] = f2h(v);
            pa += v * av4[t4];
            pb += v * bv4[t4];
            s4[t4] += v;
        }
        #pragma unroll
        for (int off = 1; off < 16; off <<= 1) {
            pa += __shfl_xor(pa, off);
            pb += __shfl_xor(pb, off);
        }
        if (li == 0) {
            fs[(size_t)h * N_NODES + row] = pa;
            fd[(size_t)h * N_NODES + row] = pb;
        }
        fdmax = fmaxf(fdmax, pb);
    }
    fdmax = fmaxf(fdmax, __shfl_xor(fdmax, 16));
    fdmax = fmaxf(fdmax, __shfl_xor(fdmax, 32));
    if (lane == 0) red[w] = fdmax;
    #pragma unroll
    for (int t4 = 0; t4 < 4; ++t4) {
        s4[t4] += __shfl_xor(s4[t4], 16);
        s4[t4] += __shfl_xor(s4[t4], 32);
    }
    if (quad == 0)
        #pragma unroll
        for (int t4 = 0; t4 < 4; ++t4) csum[w][t4 * 16 + li] = s4[t4];
    __syncthreads();
    if (t == 0)
        atomicMax(gmaxe + h, fenc(fmaxf(fmaxf(red[0], red[1]), fmaxf(red[2], red[3]))));
    if (t < 64)
        atomicAdd(&cm[h * D + t],
                  (csum[0][t] + csum[1][t] + csum[2][t] + csum[3][t]) * (1.f / (float)N_NODES));
}

// ---------------------------------------------------------------- MFMA attention aggregation (R3 shape + mask LUT)
// 128-thr blocks, 2 waves x 64 rows (F=4), j-slab split; DMA-staged B-tiles,
// 2-phase syncthreads schedule. NEW vs R10:
//  - 256x16B LDS mask LUT: per A-fragment one ds_read_b128 + 4 ANDs replaces
//    8x v_bfe + 4x v_perm (the dominant per-element VALU term, -46% A-build)
//  - E/G tables per-tile double-buffered (Et/Gt[2][128], R7-proven) instead of
//    whole-slab, to fund the LUT's 4 KB: LDS total 37,888 B -> 4 blocks/CU kept
__global__ void __launch_bounds__(128, 2) k_accum(
    const unsigned int* __restrict__ bits32,
    const short* __restrict__ WB,
    const float* __restrict__ fsb, const float* __restrict__ fdb,
    const unsigned* __restrict__ gmaxe,
    short* __restrict__ num, float* __restrict__ den, int kslab) {

    __shared__ __align__(16) short Bt[2][16 * 64 * 8];   // 32 KB
    __shared__ __align__(16) short Et[2][128];           // f16 exp(fd-gm), per-tile
    __shared__ __align__(16) short Gt[2][128];           // f16 exp(0.2*(fd-gm))
    __shared__ __align__(16) uint4 MLUT[256];            // 4 KB: byte -> 4 pair-masks

    const int h = blockIdx.y, i0 = blockIdx.x * 128, slab = blockIdx.z;
    const int t = threadIdx.x, w = t >> 6, lane = t & 63;
    const int li = lane & 15, quad = lane >> 4, k0 = quad * 8;
    const size_t ho = (size_t)h * N_NODES;
    const float  gm = fdec(gmaxe[h]);
    const float* __restrict__ fd = fdb + ho;
    const short* __restrict__ Bh = WB + (size_t)h * (N_NODES / 8) * D * 8;

    const int k_beg = slab * kslab;
    const int ntile = kslab / 128;

    auto stage = [&](int buf, int jtile) {
        const short* src = Bh + (size_t)(jtile >> 3) * (D * 8);
        #pragma unroll
        for (int p = 0; p < 8; ++p)
            gl2lds16(src + (size_t)(p * 128 + t) * 8, &Bt[buf][(p * 128 + t) * 8]);
    };
    auto stage_eg = [&](int buf, int jtile) {            // 128 j per tile, 1/thread
        const float f = fd[jtile + t];
        Et[buf][t] = f2h(__expf(f - gm));
        Gt[buf][t] = f2h(__expf(0.2f * (f - gm)));
    };

    int bito[4];
    #pragma unroll
    for (int f = 0; f < 4; ++f)
        bito[f] = (i0 + w * 64 + f * 16 + li) * (NWORDS * 2);
    stage(0, k_beg);
    stage_eg(0, k_beg);
    #pragma unroll
    for (int e = t; e < 256; e += 128) {                 // fill mask LUT (once)
        uint4 m;
        m.x = ((unsigned)sext_bit(e, 0) & 0x0000FFFFu) | ((unsigned)sext_bit(e, 1) & 0xFFFF0000u);
        m.y = ((unsigned)sext_bit(e, 2) & 0x0000FFFFu) | ((unsigned)sext_bit(e, 3) & 0xFFFF0000u);
        m.z = ((unsigned)sext_bit(e, 4) & 0x0000FFFFu) | ((unsigned)sext_bit(e, 5) & 0xFFFF0000u);
        m.w = ((unsigned)sext_bit(e, 6) & 0x0000FFFFu) | ((unsigned)sext_bit(e, 7) & 0xFFFF0000u);
        MLUT[e] = m;
    }
    f16x2 Rp[4];
    #pragma unroll
    for (int f = 0; f < 4; ++f) {
        const float rv = __expf(-0.8f * (fsb[ho + i0 + w * 64 + f * 16 + li] + gm));
        const _Float16 rh = (_Float16)rv;
        Rp[f] = (f16x2){rh, rh};
    }

    f32x4 acc[4][4], c5[4];
    #pragma unroll
    for (int f = 0; f < 4; ++f) {
        #pragma unroll
        for (int q = 0; q < 4; ++q) acc[f][q] = (f32x4){0.f, 0.f, 0.f, 0.f};
        c5[f] = (f32x4){0.f, 0.f, 0.f, 0.f};
    }
    bf16x8 ones_;
    #pragma unroll
    for (int j = 0; j < 8; ++j) ones_[j] = (short)0x3C00;    // f16 1.0
    const f16x8 ones = __builtin_bit_cast(f16x8, ones_);

    __syncthreads();   // stage(0) + EG(0) + LUT landed

    for (int tile = 0; tile < ntile; ++tile) {
        const int jt = k_beg + tile * 128;
        if (tile + 1 < ntile) {
            stage((tile + 1) & 1, jt + 128);
            stage_eg((tile + 1) & 1, jt + 128);
        }

        uint4 bw[4];
        #pragma unroll
        for (int f = 0; f < 4; ++f)
            bw[f] = *(const uint4*)&bits32[(size_t)bito[f] + (jt >> 5)];

        const short* Bl = Bt[tile & 1];
        const short* Ee = Et[tile & 1];
        const short* Gg = Gt[tile & 1];
        #pragma unroll
        for (int s = 0; s < 4; ++s) {
            const uint4 Eu = *(const uint4*)&Ee[s * 32 + k0];   // 8 f16 (broadcast per quad)
            const uint4 Gu = *(const uint4*)&Gg[s * 32 + k0];
            f16x2 Ep[4] = {bcH(Eu.x), bcH(Eu.y), bcH(Eu.z), bcH(Eu.w)};
            f16x2 Gp[4] = {bcH(Gu.x), bcH(Gu.y), bcH(Gu.z), bcH(Gu.w)};
            const short* bb = Bl + (size_t)((s * 4 + quad) * 64 + li) * 8;
            f16x8 b0 = __builtin_bit_cast(f16x8, *(const bf16x8*)(bb));
            f16x8 b1 = __builtin_bit_cast(f16x8, *(const bf16x8*)(bb + 128));
            f16x8 b2 = __builtin_bit_cast(f16x8, *(const bf16x8*)(bb + 256));
            f16x8 b3 = __builtin_bit_cast(f16x8, *(const bf16x8*)(bb + 384));
            #pragma unroll
            for (int f = 0; f < 4; ++f) {
                const unsigned int wsel = (s == 0) ? bw[f].x : (s == 1) ? bw[f].y
                                        : (s == 2) ? bw[f].z : bw[f].w;
                const unsigned int byt = (wsel >> k0) & 0xFFu;
                const uint4 mq = MLUT[byt];                     // ds_read_b128
                u32x4 au;
                {
                    const f16x2 p0 = __builtin_elementwise_max(Ep[0], Gp[0] * Rp[f]);
                    const f16x2 p1 = __builtin_elementwise_max(Ep[1], Gp[1] * Rp[f]);
                    const f16x2 p2 = __builtin_elementwise_max(Ep[2], Gp[2] * Rp[f]);
                    const f16x2 p3 = __builtin_elementwise_max(Ep[3], Gp[3] * Rp[f]);
                    au[0] = __builtin_bit_cast(unsigned, p0) & mq.x;
                    au[1] = __builtin_bit_cast(unsigned, p1) & mq.y;
                    au[2] = __builtin_bit_cast(unsigned, p2) & mq.z;
                    au[3] = __builtin_bit_cast(unsigned, p3) & mq.w;
                }
                const f16x8 a = __builtin_bit_cast(f16x8, au);
                __builtin_amdgcn_s_setprio(1);
                acc[f][0] = __builtin_amdgcn_mfma_f32_16x16x32_f16(a, b0, acc[f][0], 0, 0, 0);
                acc[f][1] = __builtin_amdgcn_mfma_f32_16x16x32_f16(a, b1, acc[f][1], 0, 0, 0);
                acc[f][2] = __builtin_amdgcn_mfma_f32_16x16x32_f16(a, b2, acc[f][2], 0, 0, 0);
                acc[f][3] = __builtin_amdgcn_mfma_f32_16x16x32_f16(a, b3, acc[f][3], 0, 0, 0);
                c5[f]     = __builtin_amdgcn_mfma_f32_16x16x32_f16(a, ones, c5[f], 0, 0, 0);
                __builtin_amdgcn_s_setprio(0);
            }
        }
        __syncthreads();   // stage/EG(t+1) landed; Bt[tile&1] free
    }

    const size_t so = (size_t)(slab * gridDim.y + h);
    #pragma unroll
    for (int f = 0; f < 4; ++f) {
        #pragma unroll
        for (int t4 = 0; t4 < 4; ++t4)
            #pragma unroll
            for (int r = 0; r < 4; ++r) {
                const int row = i0 + w * 64 + f * 16 + quad * 4 + r;
                num[(so * N_NODES + row) * D + t4 * 16 + li] = f2h(acc[f][t4][r]);
            }
        if (li == 0)
            #pragma unroll
            for (int r = 0; r < 4; ++r)
                den[so * N_NODES + i0 + w * 64 + f * 16 + quad * 4 + r] = c5[f][r];
    }
}

// ---------------------------------------------------------------- layer-1 combine FUSED INTO layer-2 GEMM (proven R10)
__global__ void __launch_bounds__(128) k_gemm2f(
    const short* __restrict__ num1, const float* __restrict__ den1,
    const float* __restrict__ cm1, const short* __restrict__ WoF,
    const float* __restrict__ av, const float* __restrict__ bv,
    short* __restrict__ WBout, float* __restrict__ fs, float* __restrict__ fd,
    unsigned* __restrict__ gmaxe, float* __restrict__ cm) {

    const int i0 = blockIdx.x * 32;
    const int t = threadIdx.x, w = t >> 6, lane = t & 63;
    const int li = lane & 15, quad = lane >> 4, k0 = quad * 8;
    const int row = i0 + w * 16 + li;          // A-row this lane owns

    // per-head denominator sums for this row
    float ds8[8];
    #pragma unroll
    for (int h = 0; h < 8; ++h) {
        float ds = 0.f;
        #pragma unroll
        for (int s = 0; s < S1; ++s)
            ds += den1[((size_t)s * H + h) * N_NODES + row];
        ds8[h] = ds;
    }

    // build the 16 A-fragments (chunk c covers cols c*32 + k0 .. +8)
    f16x8 afr[16];
    #pragma unroll
    for (int c = 0; c < 16; ++c) {
        const int col512 = c * 32 + k0;
        const int h   = col512 >> 6;
        const int col = col512 & 63;
        float v8[8] = {0.f, 0.f, 0.f, 0.f, 0.f, 0.f, 0.f, 0.f};
        #pragma unroll
        for (int s = 0; s < S1; ++s) {
            bf16x8 nv = *(const bf16x8*)&num1[(((size_t)s * H + h) * N_NODES + row) * D + col];
            #pragma unroll
            for (int j = 0; j < 8; ++j) v8[j] += h2f((unsigned short)nv[j]);
        }
        const bool  uni  = !(ds8[h] > 0.f);
        const float linv = uni ? 0.f : 1.f / ds8[h];
        bf16x8 o;
        #pragma unroll
        for (int j = 0; j < 8; ++j) {
            float v = v8[j] * linv;
            if (uni) v = cm1[h * D + col + j];
            v = v > 0.f ? v : __expf(v) - 1.f;
            o[j] = f2h(v);
        }
        afr[c] = __builtin_bit_cast(f16x8, o);
    }

    // layer-2 GEMM: A from registers, B = WoF
    f32x4 c0 = {0.f, 0.f, 0.f, 0.f}, c1 = c0, c2 = c0, c3 = c0;
    #pragma unroll
    for (int c = 0; c < 16; ++c) {
        const int kt = c * 32;
        const f16x8 a = afr[c];
        const short* bb = WoF + (size_t)((kt >> 3) + quad) * (D * 8) + li * 8;
        f16x8 b0 = __builtin_bit_cast(f16x8, *(const bf16x8*)(bb));
        f16x8 b1 = __builtin_bit_cast(f16x8, *(const bf16x8*)(bb + 128));
        f16x8 b2 = __builtin_bit_cast(f16x8, *(const bf16x8*)(bb + 256));
        f16x8 b3 = __builtin_bit_cast(f16x8, *(const bf16x8*)(bb + 384));
        c0 = __builtin_amdgcn_mfma_f32_16x16x32_f16(a, b0, c0, 0, 0, 0);
        c1 = __builtin_amdgcn_mfma_f32_16x16x32_f16(a, b1, c1, 0, 0, 0);
        c2 = __builtin_amdgcn_mfma_f32_16x16x32_f16(a, b2, c2, 0, 0, 0);
        c3 = __builtin_amdgcn_mfma_f32_16x16x32_f16(a, b3, c3, 0, 0, 0);
    }

    float av4[4], bv4[4];
    #pragma unroll
    for (int t4 = 0; t4 < 4; ++t4) {
        av4[t4] = av[t4 * 16 + li];
        bv4[t4] = bv[t4 * 16 + li];
    }
    float tiles[4][4];
    #pragma unroll
    for (int r = 0; r < 4; ++r) { tiles[0][r] = c0[r]; tiles[1][r] = c1[r]; tiles[2][r] = c2[r]; tiles[3][r] = c3[r]; }

    __shared__ float csum[2][64];
    __shared__ float red[2];
    float fdmax = -INFINITY;
    float s4[4] = {0.f, 0.f, 0.f, 0.f};

    #pragma unroll
    for (int r = 0; r < 4; ++r) {
        const int orow = i0 + w * 16 + quad * 4 + r;
        float pa = 0.f, pb = 0.f;
        #pragma unroll
        for (int t4 = 0; t4 < 4; ++t4) {
            const float v = tiles[t4][r];
            const int d = t4 * 16 + li;
            WBout[((size_t)(orow >> 3)) * (D * 8) + d * 8 + (orow & 7)] = f2h(v);
            pa += v * av4[t4];
            pb += v * bv4[t4];
            s4[t4] += v;
        }
        #pragma unroll
        for (int off = 1; off < 16; off <<= 1) {
            pa += __shfl_xor(pa, off);
            pb += __shfl_xor(pb, off);
        }
        if (li == 0) {
            fs[orow] = pa;
            fd[orow] = pb;
        }
        fdmax = fmaxf(fdmax, pb);
    }
    fdmax = fmaxf(fdmax, __shfl_xor(fdmax, 16));
    fdmax = fmaxf(fdmax, __shfl_xor(fdmax, 32));
    if (lane == 0) red[w] = fdmax;
    #pragma unroll
    for (int t4 = 0; t4 < 4; ++t4) {
        s4[t4] += __shfl_xor(s4[t4], 16);
        s4[t4] += __shfl_xor(s4[t4], 32);
    }
    if (quad == 0)
        #pragma unroll
        for (int t4 = 0; t4 < 4; ++t4) csum[w][t4 * 16 + li] = s4[t4];
    __syncthreads();
    if (t == 0)
        atomicMax(gmaxe, fenc(fmaxf(red[0], red[1])));
    if (t < 64)
        atomicAdd(&cm[t], (csum[0][t] + csum[1][t]) * (1.f / (float)N_NODES));
}

// ---------------------------------------------------------------- layer-2 combine (JS=S2) + ELU + log_softmax
__global__ void k_lsm(const short* __restrict__ num, const float* __restrict__ den,
                      const float* __restrict__ cm, float* __restrict__ out) {
    const int n    = blockIdx.x * 4 + (threadIdx.x >> 6);
    const int lane = threadIdx.x & 63;
    float v = 0.f, ds = 0.f;
    #pragma unroll
    for (int s = 0; s < S2; ++s)
        v += h2f((unsigned short)num[((size_t)s * N_NODES + n) * D + lane]);
    #pragma unroll
    for (int s = 0; s < S2; ++s) ds += den[(size_t)s * N_NODES + n];
    v = (ds > 0.f) ? v / ds : cm[lane];
    v = v > 0.f ? v : __expf(v) - 1.f;
    float mx = v;
    #pragma unroll
    for (int off = 32; off > 0; off >>= 1) mx = fmaxf(mx, __shfl_xor(mx, off));
    float ex = __expf(v - mx);
    float sum = ex;
    #pragma unroll
    for (int off = 32; off > 0; off >>= 1) sum += __shfl_xor(sum, off);
    out[(size_t)n * D + lane] = (v - mx) - __logf(sum);
}

// ----------------------------------------------------------------
extern "C" void kernel_launch(void* const* d_in, const int* in_sizes, int n_in,
                              void* d_out, int out_size, void* d_ws, size_t ws_size,
                              hipStream_t stream) {
    const float* x      = (const float*)d_in[0];
    const int*   adj    = (const int*)d_in[1];
    const float* W      = (const float*)d_in[2];
    const float* a_src  = (const float*)d_in[3];
    const float* a_dst  = (const float*)d_in[4];
    const float* W_o    = (const float*)d_in[5];
    const float* ao_src = (const float*)d_in[6];
    const float* ao_dst = (const float*)d_in[7];
    float* out = (float*)d_out;

    char* wsp = (char*)d_ws;
    size_t off = 0;
    auto alloc = [&](size_t bytes) -> void* {
        void* p = wsp + off;
        off += (bytes + 255) & ~(size_t)255;
        return p;
    };
    unsigned* adj_bits = (unsigned*)alloc((size_t)N_NODES * NWORDS * 8);
    short*    Xbf   = (short*)alloc((size_t)N_NODES * FDIM * 2);
    short*    WF1   = (short*)alloc((size_t)H * 64 * D * 8 * 2);
    short*    WoF   = (short*)alloc((size_t)64 * D * 8 * 2);
    short*    WhB   = (short*)alloc((size_t)H * N_NODES * D * 2);
    float*    fs1   = (float*)alloc((size_t)H * N_NODES * 4);
    float*    fd1   = (float*)alloc((size_t)H * N_NODES * 4);
    unsigned* gme1  = (unsigned*)alloc((size_t)H * 4);
    float*    cm1   = (float*)alloc((size_t)H * D * 4);
    short*    num1  = (short*)alloc((size_t)S1 * H * N_NODES * D * 2);
    float*    den1  = (float*)alloc((size_t)S1 * H * N_NODES * 4);
    short*    WhoB  = (short*)alloc((size_t)N_NODES * D * 2);
    float*    fs2   = (float*)alloc((size_t)N_NODES * 4);
    float*    fd2   = (float*)alloc((size_t)N_NODES * 4);
    unsigned* gme2  = (unsigned*)alloc(4);
    float*    cm2   = (float*)alloc((size_t)D * 4);
    short*    num2  = (short*)alloc((size_t)S2 * N_NODES * D * 2);
    float*    den2  = (float*)alloc((size_t)S2 * N_NODES * 4);

    k_pre  <<<dim3(1 + NB_BITS + NB_X + NB_W + NB_WO), dim3(256), 0, stream>>>(
        adj, x, W, W_o, adj_bits, Xbf, WF1, WoF, cm1, cm2, gme1, gme2);

    // layer 1 (8 heads)
    k_gemm <<<dim3(N_NODES / 64, H), dim3(256), 0, stream>>>(Xbf, WF1, a_src, a_dst,
                                                             WhB, fs1, fd1, gme1, cm1);
    k_accum<<<dim3(N_NODES / 128, H, S1), dim3(128), 0, stream>>>(adj_bits, WhB, fs1, fd1, gme1,
                                                                  num1, den1, N_NODES / S1);

    // layer-1 combine fused into layer-2 GEMM (hcat never materialized)
    k_gemm2f<<<dim3(N_NODES / 32), dim3(128), 0, stream>>>(num1, den1, cm1, WoF,
                                                           ao_src, ao_dst,
                                                           WhoB, fs2, fd2, gme2, cm2);

    // layer 2 (single output head)
    k_accum<<<dim3(N_NODES / 128, 1, S2), dim3(128), 0, stream>>>(adj_bits, WhoB, fs2, fd2, gme2,
                                                                  num2, den2, N_NODES / S2);
    k_lsm  <<<dim3(N_NODES / 4), dim3(256), 0, stream>>>(num2, den2, cm2, out);
}

// Round 13
// 184.122 us; speedup vs baseline: 5.0344x; 1.0212x over previous
//
#include <hip/hip_runtime.h>
#include <hip/hip_bf16.h>
#include <math.h>

#define N_NODES 4096
#define FDIM 512            // K of both GEMMs (F_in = H*D = 512)
#define D 64
#define H 8
#define NWORDS (N_NODES / 64)
#define S1 4                // layer-1 j-slabs  (32 rb x 8 h x 4 = 1024 blocks, proven R3)
#define S2 16               // layer-2 j-slabs  (32 rb x 16 = 512 blocks, proven R3)

typedef __attribute__((ext_vector_type(8))) short bf16x8;      // raw 16B of halfwords
typedef __attribute__((ext_vector_type(4))) float f32x4;
typedef __attribute__((ext_vector_type(8))) _Float16 f16x8;    // MFMA f16 operand
typedef __attribute__((ext_vector_type(2))) _Float16 f16x2;    // packed-pair math
typedef __attribute__((ext_vector_type(4))) unsigned int u32x4;

__device__ inline short f2h(float x) {                         // f32->f16 RNE
    _Float16 h = (_Float16)x;
    return __builtin_bit_cast(short, h);
}
__device__ inline float h2f(unsigned short u) {
    return (float)__builtin_bit_cast(_Float16, u);
}
__device__ inline f16x2 bcH(unsigned int u) { return __builtin_bit_cast(f16x2, u); }

__device__ inline int sext_bit(unsigned int v, int j) {        // all-ones iff bit j set
#if defined(__has_builtin) && __has_builtin(__builtin_amdgcn_sbfe)
    return __builtin_amdgcn_sbfe((int)v, j, 1);
#else
    return ((int)(v << (31 - j))) >> 31;
#endif
}

// monotonic float<->uint encoding so unsigned atomicMax == float max
__device__ inline unsigned fenc(float f) {
    unsigned u = __builtin_bit_cast(unsigned, f);
    return (u & 0x80000000u) ? ~u : (u | 0x80000000u);
}
__device__ inline float fdec(unsigned e) {
    unsigned u = (e & 0x80000000u) ? (e & 0x7FFFFFFFu) : ~e;
    return __builtin_bit_cast(float, u);
}

// async global->LDS 16B copy (DMA). LDS dst must be wave-uniform base + lane*16.
__device__ inline void gl2lds16(const void* g, void* l) {
#if defined(__has_builtin) && __has_builtin(__builtin_amdgcn_global_load_lds)
    __builtin_amdgcn_global_load_lds(
        (const __attribute__((address_space(1))) unsigned int*)g,
        (__attribute__((address_space(3))) unsigned int*)l, 16, 0, 0);
#else
    *(uint4*)l = *(const uint4*)g;
#endif
}

// ---------------------------------------------------------------- fused preprocessing (proven R0-R3)
#define NB_BITS (N_NODES * N_NODES / 2048)
#define NB_X    (N_NODES * FDIM / 1024)
#define NB_W    (H * FDIM * D / 256)
#define NB_WO   (FDIM * D / 256)
__global__ void k_pre(const int* __restrict__ adj, const float* __restrict__ x,
                      const float* __restrict__ W, const float* __restrict__ Wo,
                      unsigned int* __restrict__ bits32, short* __restrict__ Xbf,
                      short* __restrict__ WF, short* __restrict__ WoF,
                      float* __restrict__ cm1, float* __restrict__ cm2,
                      unsigned* __restrict__ gmaxe1, unsigned* __restrict__ gmaxe2) {
    const int b = blockIdx.x, t = threadIdx.x;
    if (b == 0) {
        for (int i = t; i < H * D; i += 256) cm1[i] = 0.f;
        if (t < D) cm2[t] = 0.f;
        if (t < H) gmaxe1[t] = 0u;
        if (t == 0) gmaxe2[0] = 0u;
        return;
    }
    if (b < 1 + NB_BITS) {
        const int tid  = (b - 1) * 256 + t;     // one byte (8 adj) per thread
        const size_t e0 = (size_t)tid * 8;
        int4 a0 = *(const int4*)&adj[e0];
        int4 a1 = *(const int4*)&adj[e0 + 4];
        unsigned by = (unsigned)(a0.x != 0)       | ((unsigned)(a0.y != 0) << 1)
                    | ((unsigned)(a0.z != 0) << 2) | ((unsigned)(a0.w != 0) << 3)
                    | ((unsigned)(a1.x != 0) << 4) | ((unsigned)(a1.y != 0) << 5)
                    | ((unsigned)(a1.z != 0) << 6) | ((unsigned)(a1.w != 0) << 7);
        unsigned v = by | (__shfl_xor((int)by, 1) << 8);
        v = v | ((unsigned)__shfl_xor((int)v, 2) << 16);
        if ((t & 3) == 0) bits32[tid >> 2] = v;
        return;
    }
    if (b < 1 + NB_BITS + NB_X) {
        const size_t i4 = ((size_t)(b - 1 - NB_BITS) * 256 + t) * 4;
        float4 v = *(const float4*)&x[i4];
        ushort4 o;
        o.x = (unsigned short)f2h(v.x); o.y = (unsigned short)f2h(v.y);
        o.z = (unsigned short)f2h(v.z); o.w = (unsigned short)f2h(v.w);
        *(ushort4*)&Xbf[i4] = o;
        return;
    }
    if (b < 1 + NB_BITS + NB_X + NB_W) {
        const size_t idx = (size_t)(b - 1 - NB_BITS - NB_X) * 256 + t;   // (h*512+k)*64+d
        const int d = idx & 63;
        const int k = (int)(idx >> 6) & 511;
        const int h = (int)(idx >> 15);
        WF[(((size_t)h * 64 + (k >> 3)) * 64 + d) * 8 + (k & 7)] = f2h(W[idx]);
        return;
    }
    {
        const size_t idx = (size_t)(b - 1 - NB_BITS - NB_X - NB_W) * 256 + t;  // k*64+d
        const int d = idx & 63;
        const int k = (int)(idx >> 6);
        WoF[(((size_t)(k >> 3)) * 64 + d) * 8 + (k & 7)] = f2h(Wo[idx]);
    }
}

// ---------------------------------------------------------------- MFMA GEMM layer-1 (proven R0-R3, 256 thr)
__global__ void __launch_bounds__(256) k_gemm(
    const short* __restrict__ Xbf, const short* __restrict__ WF,
    const float* __restrict__ av, const float* __restrict__ bv,
    short* __restrict__ WBout, float* __restrict__ fs, float* __restrict__ fd,
    unsigned* __restrict__ gmaxe, float* __restrict__ cm) {
    const int h  = blockIdx.y;
    const int i0 = blockIdx.x * 64;
    const int t = threadIdx.x, w = t >> 6, lane = t & 63;
    const int li = lane & 15, quad = lane >> 4, k0 = quad * 8;
    const int row_a = i0 + w * 16 + li;
    const short* __restrict__ Xr  = Xbf + (size_t)row_a * FDIM;
    const short* __restrict__ WFh = WF + (size_t)h * 64 * D * 8;

    f32x4 c0 = {0.f, 0.f, 0.f, 0.f}, c1 = c0, c2 = c0, c3 = c0;
    #pragma unroll 4
    for (int kt = 0; kt < FDIM; kt += 32) {
        f16x8 a = __builtin_bit_cast(f16x8, *(const bf16x8*)&Xr[kt + k0]);
        const short* bb = WFh + (size_t)((kt >> 3) + quad) * (D * 8) + li * 8;
        f16x8 b0 = __builtin_bit_cast(f16x8, *(const bf16x8*)(bb));
        f16x8 b1 = __builtin_bit_cast(f16x8, *(const bf16x8*)(bb + 128));
        f16x8 b2 = __builtin_bit_cast(f16x8, *(const bf16x8*)(bb + 256));
        f16x8 b3 = __builtin_bit_cast(f16x8, *(const bf16x8*)(bb + 384));
        c0 = __builtin_amdgcn_mfma_f32_16x16x32_f16(a, b0, c0, 0, 0, 0);
        c1 = __builtin_amdgcn_mfma_f32_16x16x32_f16(a, b1, c1, 0, 0, 0);
        c2 = __builtin_amdgcn_mfma_f32_16x16x32_f16(a, b2, c2, 0, 0, 0);
        c3 = __builtin_amdgcn_mfma_f32_16x16x32_f16(a, b3, c3, 0, 0, 0);
    }
    float av4[4], bv4[4];
    #pragma unroll
    for (int t4 = 0; t4 < 4; ++t4) {
        av4[t4] = av[h * D + t4 * 16 + li];
        bv4[t4] = bv[h * D + t4 * 16 + li];
    }
    float tiles[4][4];
    #pragma unroll
    for (int r = 0; r < 4; ++r) { tiles[0][r] = c0[r]; tiles[1][r] = c1[r]; tiles[2][r] = c2[r]; tiles[3][r] = c3[r]; }

    __shared__ float csum[4][64];
    __shared__ float red[4];
    float fdmax = -INFINITY;
    float s4[4] = {0.f, 0.f, 0.f, 0.f};

    #pragma unroll
    for (int r = 0; r < 4; ++r) {
        const int row = i0 + w * 16 + quad * 4 + r;
        float pa = 0.f, pb = 0.f;
        #pragma unroll
        for (int t4 = 0; t4 < 4; ++t4) {
            const float v = tiles[t4][r];
            const int d = t4 * 16 + li;
            WBout[((size_t)h * (N_NODES / 8) + (row >> 3)) * (D * 8) + d * 8 + (row & 7)] = f2h(v);
            pa += v * av4[t4];
            pb += v * bv4[t4];
            s4[t4] += v;
        }
        #pragma unroll
        for (int off = 1; off < 16; off <<= 1) {
            pa += __shfl_xor(pa, off);
            pb += __shfl_xor(pb, off);
        }
        if (li == 0) {
            fs[(size_t)h * N_NODES + row] = pa;
            fd[(size_t)h * N_NODES + row] = pb;
        }
        fdmax = fmaxf(fdmax, pb);
    }
    fdmax = fmaxf(fdmax, __shfl_xor(fdmax, 16));
    fdmax = fmaxf(fdmax, __shfl_xor(fdmax, 32));
    if (lane == 0) red[w] = fdmax;
    #pragma unroll
    for (int t4 = 0; t4 < 4; ++t4) {
        s4[t4] += __shfl_xor(s4[t4], 16);
        s4[t4] += __shfl_xor(s4[t4], 32);
    }
    if (quad == 0)
        #pragma unroll
        for (int t4 = 0; t4 < 4; ++t4) csum[w][t4 * 16 + li] = s4[t4];
    __syncthreads();
    if (t == 0)
        atomicMax(gmaxe + h, fenc(fmaxf(fmaxf(red[0], red[1]), fmaxf(red[2], red[3]))));
    if (t < 64)
        atomicAdd(&cm[h * D + t],
                  (csum[0][t] + csum[1][t] + csum[2][t] + csum[3][t]) * (1.f / (float)N_NODES));
}

// ---------------------------------------------------------------- MFMA attention aggregation (R11 proven: LUT + per-tile EG)
__global__ void __launch_bounds__(128, 2) k_accum(
    const unsigned int* __restrict__ bits32,
    const short* __restrict__ WB,
    const float* __restrict__ fsb, const float* __restrict__ fdb,
    const unsigned* __restrict__ gmaxe,
    short* __restrict__ num, float* __restrict__ den, int kslab) {

    __shared__ __align__(16) short Bt[2][16 * 64 * 8];   // 32 KB
    __shared__ __align__(16) short Et[2][128];           // f16 exp(fd-gm), per-tile
    __shared__ __align__(16) short Gt[2][128];           // f16 exp(0.2*(fd-gm))
    __shared__ __align__(16) uint4 MLUT[256];            // 4 KB: byte -> 4 pair-masks

    const int h = blockIdx.y, i0 = blockIdx.x * 128, slab = blockIdx.z;
    const int t = threadIdx.x, w = t >> 6, lane = t & 63;
    const int li = lane & 15, quad = lane >> 4, k0 = quad * 8;
    const size_t ho = (size_t)h * N_NODES;
    const float  gm = fdec(gmaxe[h]);
    const float* __restrict__ fd = fdb + ho;
    const short* __restrict__ Bh = WB + (size_t)h * (N_NODES / 8) * D * 8;

    const int k_beg = slab * kslab;
    const int ntile = kslab / 128;

    auto stage = [&](int buf, int jtile) {
        const short* src = Bh + (size_t)(jtile >> 3) * (D * 8);
        #pragma unroll
        for (int p = 0; p < 8; ++p)
            gl2lds16(src + (size_t)(p * 128 + t) * 8, &Bt[buf][(p * 128 + t) * 8]);
    };
    auto stage_eg = [&](int buf, int jtile) {            // 128 j per tile, 1/thread
        const float f = fd[jtile + t];
        Et[buf][t] = f2h(__expf(f - gm));
        Gt[buf][t] = f2h(__expf(0.2f * (f - gm)));
    };

    int bito[4];
    #pragma unroll
    for (int f = 0; f < 4; ++f)
        bito[f] = (i0 + w * 64 + f * 16 + li) * (NWORDS * 2);
    stage(0, k_beg);
    stage_eg(0, k_beg);
    #pragma unroll
    for (int e = t; e < 256; e += 128) {                 // fill mask LUT (once)
        uint4 m;
        m.x = ((unsigned)sext_bit(e, 0) & 0x0000FFFFu) | ((unsigned)sext_bit(e, 1) & 0xFFFF0000u);
        m.y = ((unsigned)sext_bit(e, 2) & 0x0000FFFFu) | ((unsigned)sext_bit(e, 3) & 0xFFFF0000u);
        m.z = ((unsigned)sext_bit(e, 4) & 0x0000FFFFu) | ((unsigned)sext_bit(e, 5) & 0xFFFF0000u);
        m.w = ((unsigned)sext_bit(e, 6) & 0x0000FFFFu) | ((unsigned)sext_bit(e, 7) & 0xFFFF0000u);
        MLUT[e] = m;
    }
    f16x2 Rp[4];
    #pragma unroll
    for (int f = 0; f < 4; ++f) {
        const float rv = __expf(-0.8f * (fsb[ho + i0 + w * 64 + f * 16 + li] + gm));
        const _Float16 rh = (_Float16)rv;
        Rp[f] = (f16x2){rh, rh};
    }

    f32x4 acc[4][4], c5[4];
    #pragma unroll
    for (int f = 0; f < 4; ++f) {
        #pragma unroll
        for (int q = 0; q < 4; ++q) acc[f][q] = (f32x4){0.f, 0.f, 0.f, 0.f};
        c5[f] = (f32x4){0.f, 0.f, 0.f, 0.f};
    }
    bf16x8 ones_;
    #pragma unroll
    for (int j = 0; j < 8; ++j) ones_[j] = (short)0x3C00;    // f16 1.0
    const f16x8 ones = __builtin_bit_cast(f16x8, ones_);

    __syncthreads();   // stage(0) + EG(0) + LUT landed

    for (int tile = 0; tile < ntile; ++tile) {
        const int jt = k_beg + tile * 128;
        if (tile + 1 < ntile) {
            stage((tile + 1) & 1, jt + 128);
            stage_eg((tile + 1) & 1, jt + 128);
        }

        uint4 bw[4];
        #pragma unroll
        for (int f = 0; f < 4; ++f)
            bw[f] = *(const uint4*)&bits32[(size_t)bito[f] + (jt >> 5)];

        const short* Bl = Bt[tile & 1];
        const short* Ee = Et[tile & 1];
        const short* Gg = Gt[tile & 1];
        #pragma unroll
        for (int s = 0; s < 4; ++s) {
            const uint4 Eu = *(const uint4*)&Ee[s * 32 + k0];   // 8 f16 (broadcast per quad)
            const uint4 Gu = *(const uint4*)&Gg[s * 32 + k0];
            f16x2 Ep[4] = {bcH(Eu.x), bcH(Eu.y), bcH(Eu.z), bcH(Eu.w)};
            f16x2 Gp[4] = {bcH(Gu.x), bcH(Gu.y), bcH(Gu.z), bcH(Gu.w)};
            const short* bb = Bl + (size_t)((s * 4 + quad) * 64 + li) * 8;
            f16x8 b0 = __builtin_bit_cast(f16x8, *(const bf16x8*)(bb));
            f16x8 b1 = __builtin_bit_cast(f16x8, *(const bf16x8*)(bb + 128));
            f16x8 b2 = __builtin_bit_cast(f16x8, *(const bf16x8*)(bb + 256));
            f16x8 b3 = __builtin_bit_cast(f16x8, *(const bf16x8*)(bb + 384));
            #pragma unroll
            for (int f = 0; f < 4; ++f) {
                const unsigned int wsel = (s == 0) ? bw[f].x : (s == 1) ? bw[f].y
                                        : (s == 2) ? bw[f].z : bw[f].w;
                const unsigned int byt = (wsel >> k0) & 0xFFu;
                const uint4 mq = MLUT[byt];                     // ds_read_b128
                u32x4 au;
                {
                    const f16x2 p0 = __builtin_elementwise_max(Ep[0], Gp[0] * Rp[f]);
                    const f16x2 p1 = __builtin_elementwise_max(Ep[1], Gp[1] * Rp[f]);
                    const f16x2 p2 = __builtin_elementwise_max(Ep[2], Gp[2] * Rp[f]);
                    const f16x2 p3 = __builtin_elementwise_max(Ep[3], Gp[3] * Rp[f]);
                    au[0] = __builtin_bit_cast(unsigned, p0) & mq.x;
                    au[1] = __builtin_bit_cast(unsigned, p1) & mq.y;
                    au[2] = __builtin_bit_cast(unsigned, p2) & mq.z;
                    au[3] = __builtin_bit_cast(unsigned, p3) & mq.w;
                }
                const f16x8 a = __builtin_bit_cast(f16x8, au);
                __builtin_amdgcn_s_setprio(1);
                acc[f][0] = __builtin_amdgcn_mfma_f32_16x16x32_f16(a, b0, acc[f][0], 0, 0, 0);
                acc[f][1] = __builtin_amdgcn_mfma_f32_16x16x32_f16(a, b1, acc[f][1], 0, 0, 0);
                acc[f][2] = __builtin_amdgcn_mfma_f32_16x16x32_f16(a, b2, acc[f][2], 0, 0, 0);
                acc[f][3] = __builtin_amdgcn_mfma_f32_16x16x32_f16(a, b3, acc[f][3], 0, 0, 0);
                c5[f]     = __builtin_amdgcn_mfma_f32_16x16x32_f16(a, ones, c5[f], 0, 0, 0);
                __builtin_amdgcn_s_setprio(0);
            }
        }
        __syncthreads();   // stage/EG(t+1) landed; Bt[tile&1] free
    }

    const size_t so = (size_t)(slab * gridDim.y + h);
    #pragma unroll
    for (int f = 0; f < 4; ++f) {
        #pragma unroll
        for (int t4 = 0; t4 < 4; ++t4)
            #pragma unroll
            for (int r = 0; r < 4; ++r) {
                const int row = i0 + w * 64 + f * 16 + quad * 4 + r;
                num[(so * N_NODES + row) * D + t4 * 16 + li] = f2h(acc[f][t4][r]);
            }
        if (li == 0)
            #pragma unroll
            for (int r = 0; r < 4; ++r)
                den[so * N_NODES + i0 + w * 64 + f * 16 + quad * 4 + r] = c5[f][r];
    }
}

// ---------------------------------------------------------------- layer-1 combine fused into layer-2 GEMM, 4-way K-split
// 256 blocks x 256 thr (4 waves), block = 16 rows; wave w owns K-quarter
// [w*128, w*128+128) = heads {2w,2w+1}. Partials reduced via 12 KB LDS
// (intra-block sync only); wave 0 runs the stats/WBout epilogue.
// 1024 waves = 4 waves/CU on ALL CUs; per-wave MFMA chain 16 -> 4.
__global__ void __launch_bounds__(256) k_gemm2f(
    const short* __restrict__ num1, const float* __restrict__ den1,
    const float* __restrict__ cm1, const short* __restrict__ WoF,
    const float* __restrict__ av, const float* __restrict__ bv,
    short* __restrict__ WBout, float* __restrict__ fs, float* __restrict__ fd,
    unsigned* __restrict__ gmaxe, float* __restrict__ cm) {

    __shared__ __align__(16) float psum[3][64][16];   // waves 1..3 partial tiles
    __shared__ float csum[64];

    const int i0 = blockIdx.x * 16;            // 16 rows/block
    const int t = threadIdx.x, w = t >> 6, lane = t & 63;
    const int li = lane & 15, quad = lane >> 4, k0 = quad * 8;
    const int row = i0 + li;                   // A-row this lane owns

    // denominators for this wave's two heads
    float ds2[2];
    #pragma unroll
    for (int hh = 0; hh < 2; ++hh) {
        const int h = w * 2 + hh;
        float ds = 0.f;
        #pragma unroll
        for (int s = 0; s < S1; ++s)
            ds += den1[((size_t)s * H + h) * N_NODES + row];
        ds2[hh] = ds;
    }

    // build 4 A-fragments for k in [w*128, w*128+128)
    f16x8 afr[4];
    #pragma unroll
    for (int c = 0; c < 4; ++c) {
        const int col512 = w * 128 + c * 32 + k0;
        const int h   = col512 >> 6;
        const int col = col512 & 63;
        const int hh  = h - w * 2;             // 0 or 1
        float v8[8] = {0.f, 0.f, 0.f, 0.f, 0.f, 0.f, 0.f, 0.f};
        #pragma unroll
        for (int s = 0; s < S1; ++s) {
            bf16x8 nv = *(const bf16x8*)&num1[(((size_t)s * H + h) * N_NODES + row) * D + col];
            #pragma unroll
            for (int j = 0; j < 8; ++j) v8[j] += h2f((unsigned short)nv[j]);
        }
        const bool  uni  = !(ds2[hh] > 0.f);
        const float linv = uni ? 0.f : 1.f / ds2[hh];
        bf16x8 o;
        #pragma unroll
        for (int j = 0; j < 8; ++j) {
            float v = v8[j] * linv;
            if (uni) v = cm1[h * D + col + j];
            v = v > 0.f ? v : __expf(v) - 1.f;
            o[j] = f2h(v);
        }
        afr[c] = __builtin_bit_cast(f16x8, o);
    }

    // partial GEMM over this wave's K-quarter
    f32x4 c0 = {0.f, 0.f, 0.f, 0.f}, c1 = c0, c2 = c0, c3 = c0;
    #pragma unroll
    for (int c = 0; c < 4; ++c) {
        const int kt = w * 128 + c * 32;
        const f16x8 a = afr[c];
        const short* bb = WoF + (size_t)((kt >> 3) + quad) * (D * 8) + li * 8;
        f16x8 b0 = __builtin_bit_cast(f16x8, *(const bf16x8*)(bb));
        f16x8 b1 = __builtin_bit_cast(f16x8, *(const bf16x8*)(bb + 128));
        f16x8 b2 = __builtin_bit_cast(f16x8, *(const bf16x8*)(bb + 256));
        f16x8 b3 = __builtin_bit_cast(f16x8, *(const bf16x8*)(bb + 384));
        c0 = __builtin_amdgcn_mfma_f32_16x16x32_f16(a, b0, c0, 0, 0, 0);
        c1 = __builtin_amdgcn_mfma_f32_16x16x32_f16(a, b1, c1, 0, 0, 0);
        c2 = __builtin_amdgcn_mfma_f32_16x16x32_f16(a, b2, c2, 0, 0, 0);
        c3 = __builtin_amdgcn_mfma_f32_16x16x32_f16(a, b3, c3, 0, 0, 0);
    }

    // cross-wave reduce (intra-block): waves 1..3 park partials in LDS
    if (w > 0) {
        float* dst = &psum[w - 1][lane][0];
        #pragma unroll
        for (int r = 0; r < 4; ++r) {
            dst[r]      = c0[r];
            dst[4 + r]  = c1[r];
            dst[8 + r]  = c2[r];
            dst[12 + r] = c3[r];
        }
    }
    __syncthreads();
    if (w > 0) return;

    #pragma unroll
    for (int ww = 0; ww < 3; ++ww) {
        const float* src = &psum[ww][lane][0];
        #pragma unroll
        for (int r = 0; r < 4; ++r) {
            c0[r] += src[r];
            c1[r] += src[4 + r];
            c2[r] += src[8 + r];
            c3[r] += src[12 + r];
        }
    }

    // ---- epilogue (wave 0 only): WBout + fs/fd + gmax + colmean
    float av4[4], bv4[4];
    #pragma unroll
    for (int t4 = 0; t4 < 4; ++t4) {
        av4[t4] = av[t4 * 16 + li];
        bv4[t4] = bv[t4 * 16 + li];
    }
    float tiles[4][4];
    #pragma unroll
    for (int r = 0; r < 4; ++r) { tiles[0][r] = c0[r]; tiles[1][r] = c1[r]; tiles[2][r] = c2[r]; tiles[3][r] = c3[r]; }

    float fdmax = -INFINITY;
    float s4[4] = {0.f, 0.f, 0.f, 0.f};
    #pragma unroll
    for (int r = 0; r < 4; ++r) {
        const int orow = i0 + quad * 4 + r;
        float pa = 0.f, pb = 0.f;
        #pragma unroll
        for (int t4 = 0; t4 < 4; ++t4) {
            const float v = tiles[t4][r];
            const int d = t4 * 16 + li;
            WBout[((size_t)(orow >> 3)) * (D * 8) + d * 8 + (orow & 7)] = f2h(v);
            pa += v * av4[t4];
            pb += v * bv4[t4];
            s4[t4] += v;
        }
        #pragma unroll
        for (int off = 1; off < 16; off <<= 1) {
            pa += __shfl_xor(pa, off);
            pb += __shfl_xor(pb, off);
        }
        if (li == 0) {
            fs[orow] = pa;
            fd[orow] = pb;
        }
        fdmax = fmaxf(fdmax, pb);
    }
    fdmax = fmaxf(fdmax, __shfl_xor(fdmax, 16));
    fdmax = fmaxf(fdmax, __shfl_xor(fdmax, 32));
    if (lane == 0)
        atomicMax(gmaxe, fenc(fdmax));
    #pragma unroll
    for (int t4 = 0; t4 < 4; ++t4) {
        s4[t4] += __shfl_xor(s4[t4], 16);
        s4[t4] += __shfl_xor(s4[t4], 32);
    }
    if (quad == 0)
        #pragma unroll
        for (int t4 = 0; t4 < 4; ++t4) csum[t4 * 16 + li] = s4[t4];
    // csum written by quad-0 lanes, read by the same wave below (lgkm wait auto)
    if (lane < D)
        atomicAdd(&cm[lane], csum[lane] * (1.f / (float)N_NODES));
}

// ---------------------------------------------------------------- layer-2 combine (JS=S2) + ELU + log_softmax
__global__ void k_lsm(const short* __restrict__ num, const float* __restrict__ den,
                      const float* __restrict__ cm, float* __restrict__ out) {
    const int n    = blockIdx.x * 4 + (threadIdx.x >> 6);
    const int lane = threadIdx.x & 63;
    float v = 0.f, ds = 0.f;
    #pragma unroll
    for (int s = 0; s < S2; ++s)
        v += h2f((unsigned short)num[((size_t)s * N_NODES + n) * D + lane]);
    #pragma unroll
    for (int s = 0; s < S2; ++s) ds += den[(size_t)s * N_NODES + n];
    v = (ds > 0.f) ? v / ds : cm[lane];
    v = v > 0.f ? v : __expf(v) - 1.f;
    float mx = v;
    #pragma unroll
    for (int off = 32; off > 0; off >>= 1) mx = fmaxf(mx, __shfl_xor(mx, off));
    float ex = __expf(v - mx);
    float sum = ex;
    #pragma unroll
    for (int off = 32; off > 0; off >>= 1) sum += __shfl_xor(sum, off);
    out[(size_t)n * D + lane] = (v - mx) - __logf(sum);
}

// ----------------------------------------------------------------
extern "C" void kernel_launch(void* const* d_in, const int* in_sizes, int n_in,
                              void* d_out, int out_size, void* d_ws, size_t ws_size,
                              hipStream_t stream) {
    const float* x      = (const float*)d_in[0];
    const int*   adj    = (const int*)d_in[1];
    const float* W      = (const float*)d_in[2];
    const float* a_src  = (const float*)d_in[3];
    const float* a_dst  = (const float*)d_in[4];
    const float* W_o    = (const float*)d_in[5];
    const float* ao_src = (const float*)d_in[6];
    const float* ao_dst = (const float*)d_in[7];
    float* out = (float*)d_out;

    char* wsp = (char*)d_ws;
    size_t off = 0;
    auto alloc = [&](size_t bytes) -> void* {
        void* p = wsp + off;
        off += (bytes + 255) & ~(size_t)255;
        return p;
    };
    unsigned* adj_bits = (unsigned*)alloc((size_t)N_NODES * NWORDS * 8);
    short*    Xbf   = (short*)alloc((size_t)N_NODES * FDIM * 2);
    short*    WF1   = (short*)alloc((size_t)H * 64 * D * 8 * 2);
    short*    WoF   = (short*)alloc((size_t)64 * D * 8 * 2);
    short*    WhB   = (short*)alloc((size_t)H * N_NODES * D * 2);
    float*    fs1   = (float*)alloc((size_t)H * N_NODES * 4);
    float*    fd1   = (float*)alloc((size_t)H * N_NODES * 4);
    unsigned* gme1  = (unsigned*)alloc((size_t)H * 4);
    float*    cm1   = (float*)alloc((size_t)H * D * 4);
    short*    num1  = (short*)alloc((size_t)S1 * H * N_NODES * D * 2);
    float*    den1  = (float*)alloc((size_t)S1 * H * N_NODES * 4);
    short*    WhoB  = (short*)alloc((size_t)N_NODES * D * 2);
    float*    fs2   = (float*)alloc((size_t)N_NODES * 4);
    float*    fd2   = (float*)alloc((size_t)N_NODES * 4);
    unsigned* gme2  = (unsigned*)alloc(4);
    float*    cm2   = (float*)alloc((size_t)D * 4);
    short*    num2  = (short*)alloc((size_t)S2 * N_NODES * D * 2);
    float*    den2  = (float*)alloc((size_t)S2 * N_NODES * 4);

    k_pre  <<<dim3(1 + NB_BITS + NB_X + NB_W + NB_WO), dim3(256), 0, stream>>>(
        adj, x, W, W_o, adj_bits, Xbf, WF1, WoF, cm1, cm2, gme1, gme2);

    // layer 1 (8 heads)
    k_gemm <<<dim3(N_NODES / 64, H), dim3(256), 0, stream>>>(Xbf, WF1, a_src, a_dst,
                                                             WhB, fs1, fd1, gme1, cm1);
    k_accum<<<dim3(N_NODES / 128, H, S1), dim3(128), 0, stream>>>(adj_bits, WhB, fs1, fd1, gme1,
                                                                  num1, den1, N_NODES / S1);

    // layer-1 combine fused into layer-2 GEMM (hcat never materialized)
    k_gemm2f<<<dim3(N_NODES / 16), dim3(256), 0, stream>>>(num1, den1, cm1, WoF,
                                                           ao_src, ao_dst,
                                                           WhoB, fs2, fd2, gme2, cm2);

    // layer 2 (single output head)
    k_accum<<<dim3(N_NODES / 128, 1, S2), dim3(128), 0, stream>>>(adj_bits, WhoB, fs2, fd2, gme2,
                                                                  num2, den2, N_NODES / S2);
    k_lsm  <<<dim3(N_NODES / 4), dim3(256), 0, stream>>>(num2, den2, cm2, out);
}